// Round 14
// baseline (160.561 us; speedup 1.0000x reference)
//
#include <hip/hip_runtime.h>
#include <math.h>

static constexpr int IN_CH  = 256;
static constexpr int HD1    = 64;   // HEADS*HID
static constexpr int HEADS  = 4;
static constexpr int OUT_CH = 40;
static constexpr float NEG  = 0.2f;
static constexpr int BSH    = 7;    // 128 nodes per dst-bucket
static constexpr int BRNG   = 128;

typedef __attribute__((ext_vector_type(8))) short bf16x8;
typedef __attribute__((ext_vector_type(4))) short s16x4;
typedef __attribute__((ext_vector_type(4))) float f32x4;

static __device__ __forceinline__ short f2bf(float f) {
    union { float f; unsigned u; } v; v.f = f;
    unsigned r = v.u + 0x7FFFu + ((v.u >> 16) & 1u);
    return (short)(r >> 16);
}
static __device__ __forceinline__ float bf2f(unsigned short u) {
    union { unsigned u; float f; } v; v.u = ((unsigned)u) << 16;
    return v.f;
}

// ---------------- CSR build: no pre-zeroed memory anywhere ----------------
// P1: per-block LDS histogram -> NON-ATOMIC partial[blk*B + bucket] (coalesced).
__global__ __launch_bounds__(256) void k_bhist(const int* __restrict__ dst, int* __restrict__ partial,
                                               int E, int B, int perBlk) {
    __shared__ int lcnt[4096];
    for (int i = threadIdx.x; i < B; i += 256) lcnt[i] = 0;
    __syncthreads();
    const int s0 = blockIdx.x * perBlk;
    const int s1 = min(s0 + perBlk, E);
    for (int i = s0 + threadIdx.x; i < s1; i += 256)
        atomicAdd(&lcnt[dst[i] >> BSH], 1);
    __syncthreads();
    for (int i = threadIdx.x; i < B; i += 256)
        partial[blockIdx.x * B + i] = lcnt[i];
}

// P2: single-block reduce + scan. Replaces k_balloc; needs no zeroed totals.
__global__ __launch_bounds__(512) void k_bscan(const int* __restrict__ partial, int nb,
        int* __restrict__ bcnt, int* __restrict__ ebstart, int* __restrict__ ebcur,
        int* __restrict__ sstart, int B, int n) {
    __shared__ int es[512], ss[512];
    const int t = threadIdx.x;
    int ec = 0;
    if (t < B)
        for (int b = 0; b < nb; ++b) ec += partial[b * B + t];   // coalesced across threads
    int nodes = (t < B) ? min(n - (t << BSH), BRNG) : 0;
    es[t] = ec; ss[t] = ec + nodes;
    __syncthreads();
    #pragma unroll
    for (int off = 1; off < 512; off <<= 1) {       // Hillis-Steele inclusive scan
        int eu = 0, su = 0;
        if (t >= off) { eu = es[t - off]; su = ss[t - off]; }
        __syncthreads();
        if (t >= off) { es[t] += eu; ss[t] += su; }
        __syncthreads();
    }
    if (t < B) {
        const int e0 = es[t] - ec;                  // exclusive
        bcnt[t]    = ec;
        ebstart[t] = e0;
        ebcur[t]   = e0;
        sstart[t]  = ss[t] - (ec + nodes);
    }
}

// Edge record packed to 24 bits: src (17b) << 7 | (dst & 127).
__global__ __launch_bounds__(256) void k_bpart(const int* __restrict__ ei, int* __restrict__ ebcur,
        unsigned* __restrict__ epk, int E, int B, int perBlk) {
    __shared__ int lcnt[4096];
    __shared__ int lofs[4096];
    for (int i = threadIdx.x; i < B; i += 256) lcnt[i] = 0;
    __syncthreads();
    const int s0 = blockIdx.x * perBlk;
    const int s1 = min(s0 + perBlk, E);
    for (int i = s0 + threadIdx.x; i < s1; i += 256)
        atomicAdd(&lcnt[ei[E + i] >> BSH], 1);
    __syncthreads();
    for (int i = threadIdx.x; i < B; i += 256) {
        const int c = lcnt[i];
        lofs[i] = c ? atomicAdd(&ebcur[i], c) : 0;
        lcnt[i] = 0;
    }
    __syncthreads();
    for (int i = s0 + threadIdx.x; i < s1; i += 256) {
        const int d = ei[E + i], s = ei[i];
        const int b = d >> BSH;
        const int r = atomicAdd(&lcnt[b], 1);
        epk[lofs[b] + r] = ((unsigned)s << 7) | (unsigned)(d & (BRNG - 1));
    }
}

__global__ __launch_bounds__(256) void k_bcsr(const unsigned* __restrict__ epk,
        const int* __restrict__ ebstart, const int* __restrict__ bcnt, const int* __restrict__ sstart,
        int* __restrict__ rowstart, int* __restrict__ counts, int* __restrict__ ssrc, int n) {
    __shared__ int ncnt[BRNG], rloc[BRNG], cur[BRNG];
    const int b = blockIdx.x;
    const int t = threadIdx.x;
    const int n0 = b << BSH;
    const int nodes = min(n - n0, BRNG);
    const int ec = bcnt[b];
    const int e0 = ebstart[b];
    const int s0 = sstart[b];

    if (t < BRNG) ncnt[t] = (t < nodes) ? 1 : 0;   // self-loop seed
    __syncthreads();
    for (int i = t; i < ec; i += 256)
        atomicAdd(&ncnt[epk[e0 + i] & (BRNG - 1)], 1);
    __syncthreads();

    if (t < BRNG) rloc[t] = ncnt[t];
    __syncthreads();
    #pragma unroll
    for (int off = 1; off < BRNG; off <<= 1) {      // Hillis-Steele inclusive scan
        int u = 0;
        if (t < BRNG && t >= off) u = rloc[t - off];
        __syncthreads();
        if (t < BRNG) rloc[t] += u;
        __syncthreads();
    }

    if (t < nodes) {
        const int ex = rloc[t] - ncnt[t];
        rowstart[n0 + t] = s0 + ex;
        counts[n0 + t]   = ncnt[t];
        ssrc[s0 + ex]    = n0 + t;
        cur[t] = ex + 1;
    }
    __syncthreads();
    for (int i = t; i < ec; i += 256) {
        const unsigned e = epk[e0 + i];
        const int lo = (int)(e & (BRNG - 1));
        const int p = atomicAdd(&cur[lo], 1);
        ssrc[s0 + p] = (int)(e >> 7);
    }
}

// ---------------- Layer 1 transform: h1 = x @ W1 via bf16 MFMA + fused logits ----------------
__global__ __launch_bounds__(256) void k_xform1(const float* __restrict__ x,
        const float* __restrict__ W1, const float* __restrict__ a_src, const float* __restrict__ a_dst,
        unsigned short* __restrict__ h1b, float* __restrict__ alsrc, float* __restrict__ aldst, int n)
{
    __shared__ short W1T[64][264];          // 33792 B
    const int t = threadIdx.x;
    const int l = t & 63;
    const int w = t >> 6;

    {
        const int c = l;
        #pragma unroll
        for (int i = 0; i < 16; ++i) {
            const int kb = i * 16 + w * 4;
            s16x4 pk;
            pk[0] = f2bf(W1[(kb + 0) * 64 + c]);
            pk[1] = f2bf(W1[(kb + 1) * 64 + c]);
            pk[2] = f2bf(W1[(kb + 2) * 64 + c]);
            pk[3] = f2bf(W1[(kb + 3) * 64 + c]);
            *(s16x4*)&W1T[c][kb] = pk;
        }
    }
    __syncthreads();

    const int r0 = blockIdx.x * 64 + w * 16;
    const int lr = l & 15;
    const int lk = l >> 4;

    f32x4 acc[4];
    #pragma unroll
    for (int ct = 0; ct < 4; ++ct) acc[ct] = (f32x4){0.f, 0.f, 0.f, 0.f};

    int rowA = r0 + lr; if (rowA > n - 1) rowA = n - 1;
    const float* xrow = x + (size_t)rowA * IN_CH + lk * 8;

    float4 a0 = *(const float4*)(xrow);
    float4 a1 = *(const float4*)(xrow + 4);

    for (int ks = 0; ks < 8; ++ks) {
        bf16x8 bfrag[4];
        #pragma unroll
        for (int ct = 0; ct < 4; ++ct)
            bfrag[ct] = *(const bf16x8*)&W1T[ct * 16 + lr][ks * 32 + lk * 8];

        const float4 c0 = a0, c1 = a1;
        if (ks < 7) {
            a0 = *(const float4*)(xrow + (ks + 1) * 32);
            a1 = *(const float4*)(xrow + (ks + 1) * 32 + 4);
        }
        bf16x8 afrag;
        afrag[0] = f2bf(c0.x); afrag[1] = f2bf(c0.y);
        afrag[2] = f2bf(c0.z); afrag[3] = f2bf(c0.w);
        afrag[4] = f2bf(c1.x); afrag[5] = f2bf(c1.y);
        afrag[6] = f2bf(c1.z); afrag[7] = f2bf(c1.w);

        #pragma unroll
        for (int ct = 0; ct < 4; ++ct)
            acc[ct] = __builtin_amdgcn_mfma_f32_16x16x32_bf16(afrag, bfrag[ct], acc[ct], 0, 0, 0);
    }

    #pragma unroll
    for (int ct = 0; ct < 4; ++ct) {
        #pragma unroll
        for (int reg = 0; reg < 4; ++reg) {
            const int row = r0 + lk * 4 + reg;
            if (row < n) h1b[(size_t)row * HD1 + ct * 16 + lr] = (unsigned short)f2bf(acc[ct][reg]);
        }
    }

    float asv[4], adv[4];
    #pragma unroll
    for (int ct = 0; ct < 4; ++ct) { asv[ct] = a_src[ct * 16 + lr]; adv[ct] = a_dst[ct * 16 + lr]; }

    #pragma unroll
    for (int reg = 0; reg < 4; ++reg) {
        const int row = r0 + lk * 4 + reg;
        #pragma unroll
        for (int ct = 0; ct < 4; ++ct) {
            float s1 = acc[ct][reg] * asv[ct];
            float s2 = acc[ct][reg] * adv[ct];
            s1 += __shfl_xor(s1, 1); s1 += __shfl_xor(s1, 2);
            s1 += __shfl_xor(s1, 4); s1 += __shfl_xor(s1, 8);
            s2 += __shfl_xor(s2, 1); s2 += __shfl_xor(s2, 2);
            s2 += __shfl_xor(s2, 4); s2 += __shfl_xor(s2, 8);
            if (lr == 0 && row < n) {
                alsrc[row * HEADS + ct] = s1;
                aldst[row * HEADS + ct] = s2;
            }
        }
    }
}

// ---------------- Layer 1 aggregation: 4 nodes/wave, two-phase softmax, bf16 gathers; hact in bf16 ----------------
__global__ __launch_bounds__(256) void k_aggr1(const unsigned short* __restrict__ h1b,
        const float* __restrict__ alsrc, const float* __restrict__ aldst, const float* __restrict__ b1,
        const int* __restrict__ rowstart, const int* __restrict__ counts, const int* __restrict__ ssrc,
        unsigned short* __restrict__ hactb, int n)
{
    const int wid  = (blockIdx.x * blockDim.x + threadIdx.x) >> 6;
    const int lane = threadIdx.x & 63;
    const int sub  = lane & 15;
    const int head = sub >> 2;

    int nid = wid * 4 + (lane >> 4);
    const bool valid = nid < n;
    if (!valid) nid = n - 1;

    const int rs  = rowstart[nid];
    const int cnt = valid ? counts[nid] : 0;

    int maxcnt = cnt;
    maxcnt = max(maxcnt, __shfl_xor(maxcnt, 16));
    maxcnt = max(maxcnt, __shfl_xor(maxcnt, 32));

    // Phase A: node-wide max over (edge, head) pairs.
    float m = -1e30f;
    {
        const float adA = aldst[nid * HEADS + (sub & 3)];
        const int npairs = cnt * 4, maxpairs = maxcnt * 4;
        for (int idx = sub; idx < maxpairs; idx += 16) {
            if (idx < npairs) {
                int s = ssrc[rs + (idx >> 2)];
                float l = alsrc[s * HEADS + (sub & 3)] + adA;
                l = l > 0.f ? l : NEG * l;
                m = fmaxf(m, l);
            }
        }
        #pragma unroll
        for (int off = 1; off < 16; off <<= 1) m = fmaxf(m, __shfl_xor(m, off));
    }

    // Phase B: 4-wide batched independent iterations, bf16 ushort4 gathers.
    const float adB = aldst[nid * HEADS + head];
    float d = 0.f;
    float4 acc = make_float4(0.f, 0.f, 0.f, 0.f);
    for (int i0 = 0; i0 < maxcnt; i0 += 4) {
        int  sv[4]; bool on[4];
        #pragma unroll
        for (int u = 0; u < 4; ++u) {
            const int i = i0 + u;
            on[u] = i < cnt;
            sv[u] = on[u] ? ssrc[rs + i] : 0;
        }
        ushort4 hv[4]; float lv[4];
        #pragma unroll
        for (int u = 0; u < 4; ++u) {
            hv[u] = *(const ushort4*)(h1b + (size_t)sv[u] * HD1 + sub * 4);
            lv[u] = alsrc[sv[u] * HEADS + head];
        }
        #pragma unroll
        for (int u = 0; u < 4; ++u) {
            float l = lv[u] + adB;
            l = l > 0.f ? l : NEG * l;
            const float p = on[u] ? __expf(l - m) : 0.f;
            d += p;
            acc.x = fmaf(p, bf2f(hv[u].x), acc.x);
            acc.y = fmaf(p, bf2f(hv[u].y), acc.y);
            acc.z = fmaf(p, bf2f(hv[u].z), acc.z);
            acc.w = fmaf(p, bf2f(hv[u].w), acc.w);
        }
    }

    const float inv = 1.f / (d + 1e-16f);
    const float4 bv = *(const float4*)(b1 + sub * 4);
    float4 v;
    v.x = acc.x * inv + bv.x;  v.y = acc.y * inv + bv.y;
    v.z = acc.z * inv + bv.z;  v.w = acc.w * inv + bv.w;
    v.x = v.x > 0.f ? v.x : __expf(v.x) - 1.f;   // ELU
    v.y = v.y > 0.f ? v.y : __expf(v.y) - 1.f;
    v.z = v.z > 0.f ? v.z : __expf(v.z) - 1.f;
    v.w = v.w > 0.f ? v.w : __expf(v.w) - 1.f;
    if (valid) {
        ushort4 pk;
        pk.x = (unsigned short)f2bf(v.x);
        pk.y = (unsigned short)f2bf(v.y);
        pk.z = (unsigned short)f2bf(v.z);
        pk.w = (unsigned short)f2bf(v.w);
        *(ushort4*)(hactb + (size_t)nid * HD1 + sub * 4) = pk;
    }
}

// ---------------- Layer 2 transform: h2 = hact(bf16) @ W2 (64->40) + fused logits; h2 in bf16 ----------------
__global__ __launch_bounds__(64) void k_xform2(const unsigned short* __restrict__ hinb,
        const float* __restrict__ W2, const float* __restrict__ a_src, const float* __restrict__ a_dst,
        unsigned short* __restrict__ h2b, float* __restrict__ alsrc, float* __restrict__ aldst, int n)
{
    __shared__ float Ws[HD1 * OUT_CH];       // 10240 B
    const int t = threadIdx.x;
    #pragma unroll
    for (int i = 0; i < 10; ++i) ((float4*)Ws)[i * 64 + t] = ((const float4*)W2)[i * 64 + t];
    __syncthreads();

    const int r = blockIdx.x * 64 + t;
    if (r >= n) return;

    float acc[OUT_CH];
    #pragma unroll
    for (int j = 0; j < OUT_CH; ++j) acc[j] = 0.f;

    const ushort4* hr = (const ushort4*)(hinb + (size_t)r * HD1);
    for (int kq = 0; kq < 16; ++kq) {
        const ushort4 xb = hr[kq];
        const float xf[4] = { bf2f(xb.x), bf2f(xb.y), bf2f(xb.z), bf2f(xb.w) };
        #pragma unroll
        for (int kk = 0; kk < 4; ++kk) {
            const float xs = xf[kk];
            const float* wrow = Ws + (kq * 4 + kk) * OUT_CH;
            #pragma unroll
            for (int jq = 0; jq < 10; ++jq) {
                const float4 w = *(const float4*)(wrow + jq * 4);
                acc[jq * 4 + 0] = fmaf(xs, w.x, acc[jq * 4 + 0]);
                acc[jq * 4 + 1] = fmaf(xs, w.y, acc[jq * 4 + 1]);
                acc[jq * 4 + 2] = fmaf(xs, w.z, acc[jq * 4 + 2]);
                acc[jq * 4 + 3] = fmaf(xs, w.w, acc[jq * 4 + 3]);
            }
        }
    }

    float s1 = 0.f, s2 = 0.f;
    #pragma unroll
    for (int jq = 0; jq < 10; ++jq) {
        const float4 av = ((const float4*)a_src)[jq];
        const float4 dv = ((const float4*)a_dst)[jq];
        s1 += acc[jq*4+0] * av.x + acc[jq*4+1] * av.y + acc[jq*4+2] * av.z + acc[jq*4+3] * av.w;
        s2 += acc[jq*4+0] * dv.x + acc[jq*4+1] * dv.y + acc[jq*4+2] * dv.z + acc[jq*4+3] * dv.w;
        ushort4 pk;
        pk.x = (unsigned short)f2bf(acc[jq*4+0]);
        pk.y = (unsigned short)f2bf(acc[jq*4+1]);
        pk.z = (unsigned short)f2bf(acc[jq*4+2]);
        pk.w = (unsigned short)f2bf(acc[jq*4+3]);
        *(ushort4*)(h2b + (size_t)r * OUT_CH + jq * 4) = pk;
    }
    alsrc[r] = s1;
    aldst[r] = s2;
}

// ---------------- Layer 2 aggregation: two-phase + bias + log_softmax ----------------
__global__ __launch_bounds__(256) void k_aggr2(const unsigned short* __restrict__ h2b,
        const float* __restrict__ alsrc, const float* __restrict__ aldst, const float* __restrict__ b2,
        const int* __restrict__ rowstart, const int* __restrict__ counts, const int* __restrict__ ssrc,
        float* __restrict__ out, int n)
{
    const int wid  = (blockIdx.x * blockDim.x + threadIdx.x) >> 6;
    const int lane = threadIdx.x & 63;
    const int sub  = lane & 15;
    const bool act = sub < 10;
    const int subc = act ? sub : 0;

    int nid = wid * 4 + (lane >> 4);
    const bool valid = nid < n;
    if (!valid) nid = n - 1;

    const int rs  = rowstart[nid];
    const int cnt = valid ? counts[nid] : 0;

    int maxcnt = cnt;
    maxcnt = max(maxcnt, __shfl_xor(maxcnt, 16));
    maxcnt = max(maxcnt, __shfl_xor(maxcnt, 32));

    const float ad = aldst[nid];

    // Phase A: max over edges, lanes parallel (e = sub + 16k).
    float m = -1e30f;
    for (int e = sub; e < maxcnt; e += 16) {
        if (e < cnt) {
            int s = ssrc[rs + e];
            float l = alsrc[s] + ad;
            l = l > 0.f ? l : NEG * l;
            m = fmaxf(m, l);
        }
    }
    #pragma unroll
    for (int off = 1; off < 16; off <<= 1) m = fmaxf(m, __shfl_xor(m, off));

    // Phase B: 4-wide batched, bf16 ushort4 gathers.
    float d = 0.f;
    float4 acc = make_float4(0.f, 0.f, 0.f, 0.f);
    for (int i0 = 0; i0 < maxcnt; i0 += 4) {
        int  sv[4]; bool on[4];
        #pragma unroll
        for (int u = 0; u < 4; ++u) {
            const int i = i0 + u;
            on[u] = i < cnt;
            sv[u] = on[u] ? ssrc[rs + i] : 0;
        }
        ushort4 hv[4]; float lv[4];
        #pragma unroll
        for (int u = 0; u < 4; ++u) {
            hv[u] = *(const ushort4*)(h2b + (size_t)sv[u] * OUT_CH + subc * 4);
            lv[u] = alsrc[sv[u]];
        }
        #pragma unroll
        for (int u = 0; u < 4; ++u) {
            float l = lv[u] + ad;
            l = l > 0.f ? l : NEG * l;
            const float p = on[u] ? __expf(l - m) : 0.f;
            d += p;
            acc.x = fmaf(p, bf2f(hv[u].x), acc.x);
            acc.y = fmaf(p, bf2f(hv[u].y), acc.y);
            acc.z = fmaf(p, bf2f(hv[u].z), acc.z);
            acc.w = fmaf(p, bf2f(hv[u].w), acc.w);
        }
    }

    const float inv = 1.f / (d + 1e-16f);
    const float4 bv = *(const float4*)(b2 + subc * 4);
    float4 v;
    v.x = acc.x * inv + bv.x;  v.y = acc.y * inv + bv.y;
    v.z = acc.z * inv + bv.z;  v.w = acc.w * inv + bv.w;

    float mv = act ? fmaxf(fmaxf(v.x, v.y), fmaxf(v.z, v.w)) : -1e30f;
    #pragma unroll
    for (int off = 1; off < 16; off <<= 1) mv = fmaxf(mv, __shfl_xor(mv, off));
    float ex = act ? (__expf(v.x - mv) + __expf(v.y - mv) + __expf(v.z - mv) + __expf(v.w - mv)) : 0.f;
    #pragma unroll
    for (int off = 1; off < 16; off <<= 1) ex += __shfl_xor(ex, off);
    const float lse = mv + __logf(ex);

    if (valid && act) {
        *(float4*)(out + (size_t)nid * OUT_CH + sub * 4) =
            make_float4(v.x - lse, v.y - lse, v.z - lse, v.w - lse);
    }
}

extern "C" void kernel_launch(void* const* d_in, const int* in_sizes, int n_in,
                              void* d_out, int out_size, void* d_ws, size_t ws_size,
                              hipStream_t stream) {
    const float* x      = (const float*)d_in[0];
    const int*   ei     = (const int*)d_in[1];
    const float* W1     = (const float*)d_in[2];
    const float* a_src1 = (const float*)d_in[3];
    const float* a_dst1 = (const float*)d_in[4];
    const float* b1     = (const float*)d_in[5];
    const float* W2     = (const float*)d_in[6];
    const float* a_src2 = (const float*)d_in[7];
    const float* a_dst2 = (const float*)d_in[8];
    const float* b2     = (const float*)d_in[9];
    float* out = (float*)d_out;

    const int N = in_sizes[0] / IN_CH;
    const int E = in_sizes[1] / 2;
    const int B = (N + BRNG - 1) >> BSH;     // dst-buckets

    const int perBlk = 8192;
    const int nblkE  = (E + perBlk - 1) / perBlk;

    char* p = (char*)d_ws;
    auto alloc = [&](size_t bytes) -> void* {
        void* r = (void*)p;
        p += (bytes + 255) & ~(size_t)255;
        return r;
    };
    int*   counts   = (int*)alloc((size_t)N * 4);
    int*   rowstart = (int*)alloc((size_t)N * 4);
    int*   ssrc     = (int*)alloc((size_t)(E + N) * 4);
    int*   bcnt     = (int*)alloc((size_t)B * 4);
    int*   ebstart  = (int*)alloc((size_t)B * 4);
    int*   ebcur    = (int*)alloc((size_t)B * 4);
    int*   sstart   = (int*)alloc((size_t)B * 4);
    int*   partial  = (int*)alloc((size_t)nblkE * B * 4);   // per-block histograms
    unsigned short* h1b   = (unsigned short*)alloc((size_t)N * HD1 * 2);    // bf16 messages L1
    unsigned short* h2b   = (unsigned short*)alloc((size_t)N * OUT_CH * 2); // bf16 messages L2
    unsigned short* hactb = (unsigned short*)alloc((size_t)N * HD1 * 2);    // bf16 hact
    float* alsrc1   = (float*)alloc((size_t)N * HEADS * 4);
    float* aldst1   = (float*)alloc((size_t)N * HEADS * 4);
    unsigned* epk   = (unsigned*)hactb;      // alias: epk dead before hactb is written (E*4 <= N*HD1*2)
    float* alsrc2 = alsrc1; float* aldst2 = aldst1;

    const int nblk64 = (N + 63) / 64;
    const int nblkAg = (N + 15) / 16;        // 4 nodes/wave, 4 waves/block

    k_bhist <<<nblkE, 256, 0, stream>>>(ei + E, partial, E, B, perBlk);
    k_bscan <<<1, 512, 0, stream>>>(partial, nblkE, bcnt, ebstart, ebcur, sstart, B, N);
    k_bpart <<<nblkE, 256, 0, stream>>>(ei, ebcur, epk, E, B, perBlk);
    k_bcsr  <<<B, 256, 0, stream>>>(epk, ebstart, bcnt, sstart, rowstart, counts, ssrc, N);

    k_xform1 <<<nblk64, 256, 0, stream>>>(x, W1, a_src1, a_dst1, h1b, alsrc1, aldst1, N);
    k_aggr1  <<<nblkAg, 256, 0, stream>>>(h1b, alsrc1, aldst1, b1, rowstart, counts, ssrc, hactb, N);
    k_xform2 <<<nblk64, 64, 0, stream>>>(hactb, W2, a_src2, a_dst2, h2b, alsrc2, aldst2, N);
    k_aggr2  <<<nblkAg, 256, 0, stream>>>(h2b, alsrc2, aldst2, b2, rowstart, counts, ssrc, out, N);
}

// Round 15
// 144.953 us; speedup vs baseline: 1.1077x; 1.1077x over previous
//
#include <hip/hip_runtime.h>
#include <math.h>

static constexpr int IN_CH  = 256;
static constexpr int HD1    = 64;   // HEADS*HID
static constexpr int HEADS  = 4;
static constexpr int OUT_CH = 40;
static constexpr float NEG  = 0.2f;
static constexpr int BSH    = 7;    // 128 nodes per dst-bucket
static constexpr int BRNG   = 128;

typedef __attribute__((ext_vector_type(8))) short bf16x8;
typedef __attribute__((ext_vector_type(4))) short s16x4;
typedef __attribute__((ext_vector_type(4))) float f32x4;

static __device__ __forceinline__ short f2bf(float f) {
    union { float f; unsigned u; } v; v.f = f;
    unsigned r = v.u + 0x7FFFu + ((v.u >> 16) & 1u);
    return (short)(r >> 16);
}
static __device__ __forceinline__ float bf2f(unsigned short u) {
    union { unsigned u; float f; } v; v.u = ((unsigned)u) << 16;
    return v.f;
}

// ---------------- CSR build: no pre-zeroed memory anywhere ----------------
// P1: per-block LDS histogram -> partial TRANSPOSED: partial[bucket * nb + blk].
// bscan then reads each bucket's partials CONTIGUOUSLY (fixes R14's latency chain).
__global__ __launch_bounds__(256) void k_bhist(const int* __restrict__ dst, int* __restrict__ partial,
                                               int E, int B, int nb, int perBlk) {
    __shared__ int lcnt[4096];
    for (int i = threadIdx.x; i < B; i += 256) lcnt[i] = 0;
    __syncthreads();
    const int s0 = blockIdx.x * perBlk;
    const int s1 = min(s0 + perBlk, E);
    for (int i = s0 + threadIdx.x; i < s1; i += 256)
        atomicAdd(&lcnt[dst[i] >> BSH], 1);
    __syncthreads();
    for (int i = threadIdx.x; i < B; i += 256)
        partial[i * nb + blockIdx.x] = lcnt[i];
}

// P2: single-block reduce + scan. Thread t sums a contiguous run -> loads pipeline.
__global__ __launch_bounds__(512) void k_bscan(const int* __restrict__ partial, int nb,
        int* __restrict__ bcnt, int* __restrict__ ebstart, int* __restrict__ ebcur,
        int* __restrict__ sstart, int B, int n) {
    __shared__ int es[512], ss[512];
    const int t = threadIdx.x;
    int ec = 0;
    if (t < B) {
        const int* pr = partial + (size_t)t * nb;
        #pragma unroll 4
        for (int b = 0; b < nb; ++b) ec += pr[b];    // contiguous, independent loads
    }
    int nodes = (t < B) ? min(n - (t << BSH), BRNG) : 0;
    es[t] = ec; ss[t] = ec + nodes;
    __syncthreads();
    #pragma unroll
    for (int off = 1; off < 512; off <<= 1) {        // Hillis-Steele inclusive scan
        int eu = 0, su = 0;
        if (t >= off) { eu = es[t - off]; su = ss[t - off]; }
        __syncthreads();
        if (t >= off) { es[t] += eu; ss[t] += su; }
        __syncthreads();
    }
    if (t < B) {
        const int e0 = es[t] - ec;                   // exclusive
        bcnt[t]    = ec;
        ebstart[t] = e0;
        ebcur[t]   = e0;
        sstart[t]  = ss[t] - (ec + nodes);
    }
}

// Edge record packed to 24 bits: src (17b) << 7 | (dst & 127).
__global__ __launch_bounds__(256) void k_bpart(const int* __restrict__ ei, int* __restrict__ ebcur,
        unsigned* __restrict__ epk, int E, int B, int perBlk) {
    __shared__ int lcnt[4096];
    __shared__ int lofs[4096];
    for (int i = threadIdx.x; i < B; i += 256) lcnt[i] = 0;
    __syncthreads();
    const int s0 = blockIdx.x * perBlk;
    const int s1 = min(s0 + perBlk, E);
    for (int i = s0 + threadIdx.x; i < s1; i += 256)
        atomicAdd(&lcnt[ei[E + i] >> BSH], 1);
    __syncthreads();
    for (int i = threadIdx.x; i < B; i += 256) {
        const int c = lcnt[i];
        lofs[i] = c ? atomicAdd(&ebcur[i], c) : 0;
        lcnt[i] = 0;
    }
    __syncthreads();
    for (int i = s0 + threadIdx.x; i < s1; i += 256) {
        const int d = ei[E + i], s = ei[i];
        const int b = d >> BSH;
        const int r = atomicAdd(&lcnt[b], 1);
        epk[lofs[b] + r] = ((unsigned)s << 7) | (unsigned)(d & (BRNG - 1));
    }
}

__global__ __launch_bounds__(256) void k_bcsr(const unsigned* __restrict__ epk,
        const int* __restrict__ ebstart, const int* __restrict__ bcnt, const int* __restrict__ sstart,
        int* __restrict__ rowstart, int* __restrict__ counts, int* __restrict__ ssrc, int n) {
    __shared__ int ncnt[BRNG], rloc[BRNG], cur[BRNG];
    const int b = blockIdx.x;
    const int t = threadIdx.x;
    const int n0 = b << BSH;
    const int nodes = min(n - n0, BRNG);
    const int ec = bcnt[b];
    const int e0 = ebstart[b];
    const int s0 = sstart[b];

    if (t < BRNG) ncnt[t] = (t < nodes) ? 1 : 0;   // self-loop seed
    __syncthreads();
    for (int i = t; i < ec; i += 256)
        atomicAdd(&ncnt[epk[e0 + i] & (BRNG - 1)], 1);
    __syncthreads();

    if (t < BRNG) rloc[t] = ncnt[t];
    __syncthreads();
    #pragma unroll
    for (int off = 1; off < BRNG; off <<= 1) {      // Hillis-Steele inclusive scan
        int u = 0;
        if (t < BRNG && t >= off) u = rloc[t - off];
        __syncthreads();
        if (t < BRNG) rloc[t] += u;
        __syncthreads();
    }

    if (t < nodes) {
        const int ex = rloc[t] - ncnt[t];
        rowstart[n0 + t] = s0 + ex;
        counts[n0 + t]   = ncnt[t];
        ssrc[s0 + ex]    = n0 + t;
        cur[t] = ex + 1;
    }
    __syncthreads();
    for (int i = t; i < ec; i += 256) {
        const unsigned e = epk[e0 + i];
        const int lo = (int)(e & (BRNG - 1));
        const int p = atomicAdd(&cur[lo], 1);
        ssrc[s0 + p] = (int)(e >> 7);
    }
}

// ---------------- Layer 1 transform: h1 = x @ W1 via bf16 MFMA + fused logits ----------------
__global__ __launch_bounds__(256) void k_xform1(const float* __restrict__ x,
        const float* __restrict__ W1, const float* __restrict__ a_src, const float* __restrict__ a_dst,
        unsigned short* __restrict__ h1b, float* __restrict__ alsrc, float* __restrict__ aldst, int n)
{
    __shared__ short W1T[64][264];          // 33792 B
    const int t = threadIdx.x;
    const int l = t & 63;
    const int w = t >> 6;

    {
        const int c = l;
        #pragma unroll
        for (int i = 0; i < 16; ++i) {
            const int kb = i * 16 + w * 4;
            s16x4 pk;
            pk[0] = f2bf(W1[(kb + 0) * 64 + c]);
            pk[1] = f2bf(W1[(kb + 1) * 64 + c]);
            pk[2] = f2bf(W1[(kb + 2) * 64 + c]);
            pk[3] = f2bf(W1[(kb + 3) * 64 + c]);
            *(s16x4*)&W1T[c][kb] = pk;
        }
    }
    __syncthreads();

    const int r0 = blockIdx.x * 64 + w * 16;
    const int lr = l & 15;
    const int lk = l >> 4;

    f32x4 acc[4];
    #pragma unroll
    for (int ct = 0; ct < 4; ++ct) acc[ct] = (f32x4){0.f, 0.f, 0.f, 0.f};

    int rowA = r0 + lr; if (rowA > n - 1) rowA = n - 1;
    const float* xrow = x + (size_t)rowA * IN_CH + lk * 8;

    float4 a0 = *(const float4*)(xrow);
    float4 a1 = *(const float4*)(xrow + 4);

    for (int ks = 0; ks < 8; ++ks) {
        bf16x8 bfrag[4];
        #pragma unroll
        for (int ct = 0; ct < 4; ++ct)
            bfrag[ct] = *(const bf16x8*)&W1T[ct * 16 + lr][ks * 32 + lk * 8];

        const float4 c0 = a0, c1 = a1;
        if (ks < 7) {
            a0 = *(const float4*)(xrow + (ks + 1) * 32);
            a1 = *(const float4*)(xrow + (ks + 1) * 32 + 4);
        }
        bf16x8 afrag;
        afrag[0] = f2bf(c0.x); afrag[1] = f2bf(c0.y);
        afrag[2] = f2bf(c0.z); afrag[3] = f2bf(c0.w);
        afrag[4] = f2bf(c1.x); afrag[5] = f2bf(c1.y);
        afrag[6] = f2bf(c1.z); afrag[7] = f2bf(c1.w);

        #pragma unroll
        for (int ct = 0; ct < 4; ++ct)
            acc[ct] = __builtin_amdgcn_mfma_f32_16x16x32_bf16(afrag, bfrag[ct], acc[ct], 0, 0, 0);
    }

    #pragma unroll
    for (int ct = 0; ct < 4; ++ct) {
        #pragma unroll
        for (int reg = 0; reg < 4; ++reg) {
            const int row = r0 + lk * 4 + reg;
            if (row < n) h1b[(size_t)row * HD1 + ct * 16 + lr] = (unsigned short)f2bf(acc[ct][reg]);
        }
    }

    float asv[4], adv[4];
    #pragma unroll
    for (int ct = 0; ct < 4; ++ct) { asv[ct] = a_src[ct * 16 + lr]; adv[ct] = a_dst[ct * 16 + lr]; }

    #pragma unroll
    for (int reg = 0; reg < 4; ++reg) {
        const int row = r0 + lk * 4 + reg;
        #pragma unroll
        for (int ct = 0; ct < 4; ++ct) {
            float s1 = acc[ct][reg] * asv[ct];
            float s2 = acc[ct][reg] * adv[ct];
            s1 += __shfl_xor(s1, 1); s1 += __shfl_xor(s1, 2);
            s1 += __shfl_xor(s1, 4); s1 += __shfl_xor(s1, 8);
            s2 += __shfl_xor(s2, 1); s2 += __shfl_xor(s2, 2);
            s2 += __shfl_xor(s2, 4); s2 += __shfl_xor(s2, 8);
            if (lr == 0 && row < n) {
                alsrc[row * HEADS + ct] = s1;
                aldst[row * HEADS + ct] = s2;
            }
        }
    }
}

// ---------------- Layer 1 aggregation: 4 nodes/wave, two-phase softmax, bf16 gathers; hact in bf16 ----------------
__global__ __launch_bounds__(256) void k_aggr1(const unsigned short* __restrict__ h1b,
        const float* __restrict__ alsrc, const float* __restrict__ aldst, const float* __restrict__ b1,
        const int* __restrict__ rowstart, const int* __restrict__ counts, const int* __restrict__ ssrc,
        unsigned short* __restrict__ hactb, int n)
{
    const int wid  = (blockIdx.x * blockDim.x + threadIdx.x) >> 6;
    const int lane = threadIdx.x & 63;
    const int sub  = lane & 15;
    const int head = sub >> 2;

    int nid = wid * 4 + (lane >> 4);
    const bool valid = nid < n;
    if (!valid) nid = n - 1;

    const int rs  = rowstart[nid];
    const int cnt = valid ? counts[nid] : 0;

    int maxcnt = cnt;
    maxcnt = max(maxcnt, __shfl_xor(maxcnt, 16));
    maxcnt = max(maxcnt, __shfl_xor(maxcnt, 32));

    // Phase A: node-wide max over (edge, head) pairs.
    float m = -1e30f;
    {
        const float adA = aldst[nid * HEADS + (sub & 3)];
        const int npairs = cnt * 4, maxpairs = maxcnt * 4;
        for (int idx = sub; idx < maxpairs; idx += 16) {
            if (idx < npairs) {
                int s = ssrc[rs + (idx >> 2)];
                float l = alsrc[s * HEADS + (sub & 3)] + adA;
                l = l > 0.f ? l : NEG * l;
                m = fmaxf(m, l);
            }
        }
        #pragma unroll
        for (int off = 1; off < 16; off <<= 1) m = fmaxf(m, __shfl_xor(m, off));
    }

    // Phase B: 4-wide batched independent iterations, bf16 ushort4 gathers.
    const float adB = aldst[nid * HEADS + head];
    float d = 0.f;
    float4 acc = make_float4(0.f, 0.f, 0.f, 0.f);
    for (int i0 = 0; i0 < maxcnt; i0 += 4) {
        int  sv[4]; bool on[4];
        #pragma unroll
        for (int u = 0; u < 4; ++u) {
            const int i = i0 + u;
            on[u] = i < cnt;
            sv[u] = on[u] ? ssrc[rs + i] : 0;
        }
        ushort4 hv[4]; float lv[4];
        #pragma unroll
        for (int u = 0; u < 4; ++u) {
            hv[u] = *(const ushort4*)(h1b + (size_t)sv[u] * HD1 + sub * 4);
            lv[u] = alsrc[sv[u] * HEADS + head];
        }
        #pragma unroll
        for (int u = 0; u < 4; ++u) {
            float l = lv[u] + adB;
            l = l > 0.f ? l : NEG * l;
            const float p = on[u] ? __expf(l - m) : 0.f;
            d += p;
            acc.x = fmaf(p, bf2f(hv[u].x), acc.x);
            acc.y = fmaf(p, bf2f(hv[u].y), acc.y);
            acc.z = fmaf(p, bf2f(hv[u].z), acc.z);
            acc.w = fmaf(p, bf2f(hv[u].w), acc.w);
        }
    }

    const float inv = 1.f / (d + 1e-16f);
    const float4 bv = *(const float4*)(b1 + sub * 4);
    float4 v;
    v.x = acc.x * inv + bv.x;  v.y = acc.y * inv + bv.y;
    v.z = acc.z * inv + bv.z;  v.w = acc.w * inv + bv.w;
    v.x = v.x > 0.f ? v.x : __expf(v.x) - 1.f;   // ELU
    v.y = v.y > 0.f ? v.y : __expf(v.y) - 1.f;
    v.z = v.z > 0.f ? v.z : __expf(v.z) - 1.f;
    v.w = v.w > 0.f ? v.w : __expf(v.w) - 1.f;
    if (valid) {
        ushort4 pk;
        pk.x = (unsigned short)f2bf(v.x);
        pk.y = (unsigned short)f2bf(v.y);
        pk.z = (unsigned short)f2bf(v.z);
        pk.w = (unsigned short)f2bf(v.w);
        *(ushort4*)(hactb + (size_t)nid * HD1 + sub * 4) = pk;
    }
}

// ---------------- Layer 2 transform: h2 = hact(bf16) @ W2 (64->40) + fused logits; h2 in bf16 ----------------
__global__ __launch_bounds__(64) void k_xform2(const unsigned short* __restrict__ hinb,
        const float* __restrict__ W2, const float* __restrict__ a_src, const float* __restrict__ a_dst,
        unsigned short* __restrict__ h2b, float* __restrict__ alsrc, float* __restrict__ aldst, int n)
{
    __shared__ float Ws[HD1 * OUT_CH];       // 10240 B
    const int t = threadIdx.x;
    #pragma unroll
    for (int i = 0; i < 10; ++i) ((float4*)Ws)[i * 64 + t] = ((const float4*)W2)[i * 64 + t];
    __syncthreads();

    const int r = blockIdx.x * 64 + t;
    if (r >= n) return;

    float acc[OUT_CH];
    #pragma unroll
    for (int j = 0; j < OUT_CH; ++j) acc[j] = 0.f;

    const ushort4* hr = (const ushort4*)(hinb + (size_t)r * HD1);
    for (int kq = 0; kq < 16; ++kq) {
        const ushort4 xb = hr[kq];
        const float xf[4] = { bf2f(xb.x), bf2f(xb.y), bf2f(xb.z), bf2f(xb.w) };
        #pragma unroll
        for (int kk = 0; kk < 4; ++kk) {
            const float xs = xf[kk];
            const float* wrow = Ws + (kq * 4 + kk) * OUT_CH;
            #pragma unroll
            for (int jq = 0; jq < 10; ++jq) {
                const float4 w = *(const float4*)(wrow + jq * 4);
                acc[jq * 4 + 0] = fmaf(xs, w.x, acc[jq * 4 + 0]);
                acc[jq * 4 + 1] = fmaf(xs, w.y, acc[jq * 4 + 1]);
                acc[jq * 4 + 2] = fmaf(xs, w.z, acc[jq * 4 + 2]);
                acc[jq * 4 + 3] = fmaf(xs, w.w, acc[jq * 4 + 3]);
            }
        }
    }

    float s1 = 0.f, s2 = 0.f;
    #pragma unroll
    for (int jq = 0; jq < 10; ++jq) {
        const float4 av = ((const float4*)a_src)[jq];
        const float4 dv = ((const float4*)a_dst)[jq];
        s1 += acc[jq*4+0] * av.x + acc[jq*4+1] * av.y + acc[jq*4+2] * av.z + acc[jq*4+3] * av.w;
        s2 += acc[jq*4+0] * dv.x + acc[jq*4+1] * dv.y + acc[jq*4+2] * dv.z + acc[jq*4+3] * dv.w;
        ushort4 pk;
        pk.x = (unsigned short)f2bf(acc[jq*4+0]);
        pk.y = (unsigned short)f2bf(acc[jq*4+1]);
        pk.z = (unsigned short)f2bf(acc[jq*4+2]);
        pk.w = (unsigned short)f2bf(acc[jq*4+3]);
        *(ushort4*)(h2b + (size_t)r * OUT_CH + jq * 4) = pk;
    }
    alsrc[r] = s1;
    aldst[r] = s2;
}

// ---------------- Layer 2 aggregation: two-phase + bias + log_softmax ----------------
__global__ __launch_bounds__(256) void k_aggr2(const unsigned short* __restrict__ h2b,
        const float* __restrict__ alsrc, const float* __restrict__ aldst, const float* __restrict__ b2,
        const int* __restrict__ rowstart, const int* __restrict__ counts, const int* __restrict__ ssrc,
        float* __restrict__ out, int n)
{
    const int wid  = (blockIdx.x * blockDim.x + threadIdx.x) >> 6;
    const int lane = threadIdx.x & 63;
    const int sub  = lane & 15;
    const bool act = sub < 10;
    const int subc = act ? sub : 0;

    int nid = wid * 4 + (lane >> 4);
    const bool valid = nid < n;
    if (!valid) nid = n - 1;

    const int rs  = rowstart[nid];
    const int cnt = valid ? counts[nid] : 0;

    int maxcnt = cnt;
    maxcnt = max(maxcnt, __shfl_xor(maxcnt, 16));
    maxcnt = max(maxcnt, __shfl_xor(maxcnt, 32));

    const float ad = aldst[nid];

    // Phase A: max over edges, lanes parallel (e = sub + 16k).
    float m = -1e30f;
    for (int e = sub; e < maxcnt; e += 16) {
        if (e < cnt) {
            int s = ssrc[rs + e];
            float l = alsrc[s] + ad;
            l = l > 0.f ? l : NEG * l;
            m = fmaxf(m, l);
        }
    }
    #pragma unroll
    for (int off = 1; off < 16; off <<= 1) m = fmaxf(m, __shfl_xor(m, off));

    // Phase B: 4-wide batched, bf16 ushort4 gathers.
    float d = 0.f;
    float4 acc = make_float4(0.f, 0.f, 0.f, 0.f);
    for (int i0 = 0; i0 < maxcnt; i0 += 4) {
        int  sv[4]; bool on[4];
        #pragma unroll
        for (int u = 0; u < 4; ++u) {
            const int i = i0 + u;
            on[u] = i < cnt;
            sv[u] = on[u] ? ssrc[rs + i] : 0;
        }
        ushort4 hv[4]; float lv[4];
        #pragma unroll
        for (int u = 0; u < 4; ++u) {
            hv[u] = *(const ushort4*)(h2b + (size_t)sv[u] * OUT_CH + subc * 4);
            lv[u] = alsrc[sv[u]];
        }
        #pragma unroll
        for (int u = 0; u < 4; ++u) {
            float l = lv[u] + ad;
            l = l > 0.f ? l : NEG * l;
            const float p = on[u] ? __expf(l - m) : 0.f;
            d += p;
            acc.x = fmaf(p, bf2f(hv[u].x), acc.x);
            acc.y = fmaf(p, bf2f(hv[u].y), acc.y);
            acc.z = fmaf(p, bf2f(hv[u].z), acc.z);
            acc.w = fmaf(p, bf2f(hv[u].w), acc.w);
        }
    }

    const float inv = 1.f / (d + 1e-16f);
    const float4 bv = *(const float4*)(b2 + subc * 4);
    float4 v;
    v.x = acc.x * inv + bv.x;  v.y = acc.y * inv + bv.y;
    v.z = acc.z * inv + bv.z;  v.w = acc.w * inv + bv.w;

    float mv = act ? fmaxf(fmaxf(v.x, v.y), fmaxf(v.z, v.w)) : -1e30f;
    #pragma unroll
    for (int off = 1; off < 16; off <<= 1) mv = fmaxf(mv, __shfl_xor(mv, off));
    float ex = act ? (__expf(v.x - mv) + __expf(v.y - mv) + __expf(v.z - mv) + __expf(v.w - mv)) : 0.f;
    #pragma unroll
    for (int off = 1; off < 16; off <<= 1) ex += __shfl_xor(ex, off);
    const float lse = mv + __logf(ex);

    if (valid && act) {
        *(float4*)(out + (size_t)nid * OUT_CH + sub * 4) =
            make_float4(v.x - lse, v.y - lse, v.z - lse, v.w - lse);
    }
}

extern "C" void kernel_launch(void* const* d_in, const int* in_sizes, int n_in,
                              void* d_out, int out_size, void* d_ws, size_t ws_size,
                              hipStream_t stream) {
    const float* x      = (const float*)d_in[0];
    const int*   ei     = (const int*)d_in[1];
    const float* W1     = (const float*)d_in[2];
    const float* a_src1 = (const float*)d_in[3];
    const float* a_dst1 = (const float*)d_in[4];
    const float* b1     = (const float*)d_in[5];
    const float* W2     = (const float*)d_in[6];
    const float* a_src2 = (const float*)d_in[7];
    const float* a_dst2 = (const float*)d_in[8];
    const float* b2     = (const float*)d_in[9];
    float* out = (float*)d_out;

    const int N = in_sizes[0] / IN_CH;
    const int E = in_sizes[1] / 2;
    const int B = (N + BRNG - 1) >> BSH;     // dst-buckets

    const int perBlk = 8192;
    const int nblkE  = (E + perBlk - 1) / perBlk;

    char* p = (char*)d_ws;
    auto alloc = [&](size_t bytes) -> void* {
        void* r = (void*)p;
        p += (bytes + 255) & ~(size_t)255;
        return r;
    };
    int*   counts   = (int*)alloc((size_t)N * 4);
    int*   rowstart = (int*)alloc((size_t)N * 4);
    int*   ssrc     = (int*)alloc((size_t)(E + N) * 4);
    int*   bcnt     = (int*)alloc((size_t)B * 4);
    int*   ebstart  = (int*)alloc((size_t)B * 4);
    int*   ebcur    = (int*)alloc((size_t)B * 4);
    int*   sstart   = (int*)alloc((size_t)B * 4);
    int*   partial  = (int*)alloc((size_t)B * nblkE * 4);   // transposed per-block histograms
    unsigned short* h1b   = (unsigned short*)alloc((size_t)N * HD1 * 2);    // bf16 messages L1
    unsigned short* h2b   = (unsigned short*)alloc((size_t)N * OUT_CH * 2); // bf16 messages L2
    unsigned short* hactb = (unsigned short*)alloc((size_t)N * HD1 * 2);    // bf16 hact
    float* alsrc1   = (float*)alloc((size_t)N * HEADS * 4);
    float* aldst1   = (float*)alloc((size_t)N * HEADS * 4);
    unsigned* epk   = (unsigned*)hactb;      // alias: epk dead before hactb is written (E*4 <= N*HD1*2)
    float* alsrc2 = alsrc1; float* aldst2 = aldst1;

    const int nblk64 = (N + 63) / 64;
    const int nblkAg = (N + 15) / 16;        // 4 nodes/wave, 4 waves/block

    k_bhist <<<nblkE, 256, 0, stream>>>(ei + E, partial, E, B, nblkE, perBlk);
    k_bscan <<<1, 512, 0, stream>>>(partial, nblkE, bcnt, ebstart, ebcur, sstart, B, N);
    k_bpart <<<nblkE, 256, 0, stream>>>(ei, ebcur, epk, E, B, perBlk);
    k_bcsr  <<<B, 256, 0, stream>>>(epk, ebstart, bcnt, sstart, rowstart, counts, ssrc, N);

    k_xform1 <<<nblk64, 256, 0, stream>>>(x, W1, a_src1, a_dst1, h1b, alsrc1, aldst1, N);
    k_aggr1  <<<nblkAg, 256, 0, stream>>>(h1b, alsrc1, aldst1, b1, rowstart, counts, ssrc, hactb, N);
    k_xform2 <<<nblk64, 64, 0, stream>>>(hactb, W2, a_src2, a_dst2, h2b, alsrc2, aldst2, N);
    k_aggr2  <<<nblkAg, 256, 0, stream>>>(h2b, alsrc2, aldst2, b2, rowstart, counts, ssrc, out, N);
}

// Round 16
// 142.937 us; speedup vs baseline: 1.1233x; 1.0141x over previous
//
#include <hip/hip_runtime.h>
#include <math.h>

static constexpr int IN_CH  = 256;
static constexpr int HD1    = 64;   // HEADS*HID
static constexpr int HEADS  = 4;
static constexpr int OUT_CH = 40;
static constexpr float NEG  = 0.2f;
static constexpr int BSH    = 7;    // 128 nodes per dst-bucket
static constexpr int BRNG   = 128;

typedef __attribute__((ext_vector_type(8))) short bf16x8;
typedef __attribute__((ext_vector_type(4))) short s16x4;
typedef __attribute__((ext_vector_type(4))) float f32x4;

static __device__ __forceinline__ short f2bf(float f) {
    union { float f; unsigned u; } v; v.f = f;
    unsigned r = v.u + 0x7FFFu + ((v.u >> 16) & 1u);
    return (short)(r >> 16);
}
static __device__ __forceinline__ float bf2f(unsigned short u) {
    union { unsigned u; float f; } v; v.u = ((unsigned)u) << 16;
    return v.f;
}

// ---------------- CSR build: no pre-zeroed memory anywhere ----------------
__global__ __launch_bounds__(256) void k_bhist(const int* __restrict__ dst, int* __restrict__ partial,
                                               int E, int B, int nb, int perBlk) {
    __shared__ int lcnt[4096];
    for (int i = threadIdx.x; i < B; i += 256) lcnt[i] = 0;
    __syncthreads();
    const int s0 = blockIdx.x * perBlk;
    const int s1 = min(s0 + perBlk, E);
    for (int i = s0 + threadIdx.x; i < s1; i += 256)
        atomicAdd(&lcnt[dst[i] >> BSH], 1);
    __syncthreads();
    for (int i = threadIdx.x; i < B; i += 256)
        partial[i * nb + blockIdx.x] = lcnt[i];   // transposed: bscan reads contiguously
}

__global__ __launch_bounds__(512) void k_bscan(const int* __restrict__ partial, int nb,
        int* __restrict__ bcnt, int* __restrict__ ebstart, int* __restrict__ ebcur,
        int* __restrict__ sstart, int B, int n) {
    __shared__ int es[512], ss[512];
    const int t = threadIdx.x;
    int ec = 0;
    if (t < B) {
        const int* pr = partial + (size_t)t * nb;
        #pragma unroll 4
        for (int b = 0; b < nb; ++b) ec += pr[b];    // contiguous, independent loads
    }
    int nodes = (t < B) ? min(n - (t << BSH), BRNG) : 0;
    es[t] = ec; ss[t] = ec + nodes;
    __syncthreads();
    #pragma unroll
    for (int off = 1; off < 512; off <<= 1) {        // Hillis-Steele inclusive scan
        int eu = 0, su = 0;
        if (t >= off) { eu = es[t - off]; su = ss[t - off]; }
        __syncthreads();
        if (t >= off) { es[t] += eu; ss[t] += su; }
        __syncthreads();
    }
    if (t < B) {
        const int e0 = es[t] - ec;                   // exclusive
        bcnt[t]    = ec;
        ebstart[t] = e0;
        ebcur[t]   = e0;
        sstart[t]  = ss[t] - (ec + nodes);
    }
}

// Edge record packed to 24 bits: src (17b) << 7 | (dst & 127).
__global__ __launch_bounds__(256) void k_bpart(const int* __restrict__ ei, int* __restrict__ ebcur,
        unsigned* __restrict__ epk, int E, int B, int perBlk) {
    __shared__ int lcnt[4096];
    __shared__ int lofs[4096];
    for (int i = threadIdx.x; i < B; i += 256) lcnt[i] = 0;
    __syncthreads();
    const int s0 = blockIdx.x * perBlk;
    const int s1 = min(s0 + perBlk, E);
    for (int i = s0 + threadIdx.x; i < s1; i += 256)
        atomicAdd(&lcnt[ei[E + i] >> BSH], 1);
    __syncthreads();
    for (int i = threadIdx.x; i < B; i += 256) {
        const int c = lcnt[i];
        lofs[i] = c ? atomicAdd(&ebcur[i], c) : 0;
        lcnt[i] = 0;
    }
    __syncthreads();
    for (int i = s0 + threadIdx.x; i < s1; i += 256) {
        const int d = ei[E + i], s = ei[i];
        const int b = d >> BSH;
        const int r = atomicAdd(&lcnt[b], 1);
        epk[lofs[b] + r] = ((unsigned)s << 7) | (unsigned)(d & (BRNG - 1));
    }
}

__global__ __launch_bounds__(256) void k_bcsr(const unsigned* __restrict__ epk,
        const int* __restrict__ ebstart, const int* __restrict__ bcnt, const int* __restrict__ sstart,
        int* __restrict__ rowstart, int* __restrict__ counts, int* __restrict__ ssrc, int n) {
    __shared__ int ncnt[BRNG], rloc[BRNG], cur[BRNG];
    const int b = blockIdx.x;
    const int t = threadIdx.x;
    const int n0 = b << BSH;
    const int nodes = min(n - n0, BRNG);
    const int ec = bcnt[b];
    const int e0 = ebstart[b];
    const int s0 = sstart[b];

    if (t < BRNG) ncnt[t] = (t < nodes) ? 1 : 0;   // self-loop seed
    __syncthreads();
    for (int i = t; i < ec; i += 256)
        atomicAdd(&ncnt[epk[e0 + i] & (BRNG - 1)], 1);
    __syncthreads();

    if (t < BRNG) rloc[t] = ncnt[t];
    __syncthreads();
    #pragma unroll
    for (int off = 1; off < BRNG; off <<= 1) {      // Hillis-Steele inclusive scan
        int u = 0;
        if (t < BRNG && t >= off) u = rloc[t - off];
        __syncthreads();
        if (t < BRNG) rloc[t] += u;
        __syncthreads();
    }

    if (t < nodes) {
        const int ex = rloc[t] - ncnt[t];
        rowstart[n0 + t] = s0 + ex;
        counts[n0 + t]   = ncnt[t];
        ssrc[s0 + ex]    = n0 + t;
        cur[t] = ex + 1;
    }
    __syncthreads();
    for (int i = t; i < ec; i += 256) {
        const unsigned e = epk[e0 + i];
        const int lo = (int)(e & (BRNG - 1));
        const int p = atomicAdd(&cur[lo], 1);
        ssrc[s0 + p] = (int)(e >> 7);
    }
}

// ---------------- Layer 1 transform: h1 = x @ W1 via bf16 MFMA + fused logits ----------------
__global__ __launch_bounds__(256) void k_xform1(const float* __restrict__ x,
        const float* __restrict__ W1, const float* __restrict__ a_src, const float* __restrict__ a_dst,
        unsigned short* __restrict__ h1b, float* __restrict__ alsrc, float* __restrict__ aldst, int n)
{
    __shared__ short W1T[64][264];          // 33792 B
    const int t = threadIdx.x;
    const int l = t & 63;
    const int w = t >> 6;

    {
        const int c = l;
        #pragma unroll
        for (int i = 0; i < 16; ++i) {
            const int kb = i * 16 + w * 4;
            s16x4 pk;
            pk[0] = f2bf(W1[(kb + 0) * 64 + c]);
            pk[1] = f2bf(W1[(kb + 1) * 64 + c]);
            pk[2] = f2bf(W1[(kb + 2) * 64 + c]);
            pk[3] = f2bf(W1[(kb + 3) * 64 + c]);
            *(s16x4*)&W1T[c][kb] = pk;
        }
    }
    __syncthreads();

    const int r0 = blockIdx.x * 64 + w * 16;
    const int lr = l & 15;
    const int lk = l >> 4;

    f32x4 acc[4];
    #pragma unroll
    for (int ct = 0; ct < 4; ++ct) acc[ct] = (f32x4){0.f, 0.f, 0.f, 0.f};

    int rowA = r0 + lr; if (rowA > n - 1) rowA = n - 1;
    const float* xrow = x + (size_t)rowA * IN_CH + lk * 8;

    float4 a0 = *(const float4*)(xrow);
    float4 a1 = *(const float4*)(xrow + 4);

    for (int ks = 0; ks < 8; ++ks) {
        bf16x8 bfrag[4];
        #pragma unroll
        for (int ct = 0; ct < 4; ++ct)
            bfrag[ct] = *(const bf16x8*)&W1T[ct * 16 + lr][ks * 32 + lk * 8];

        const float4 c0 = a0, c1 = a1;
        if (ks < 7) {
            a0 = *(const float4*)(xrow + (ks + 1) * 32);
            a1 = *(const float4*)(xrow + (ks + 1) * 32 + 4);
        }
        bf16x8 afrag;
        afrag[0] = f2bf(c0.x); afrag[1] = f2bf(c0.y);
        afrag[2] = f2bf(c0.z); afrag[3] = f2bf(c0.w);
        afrag[4] = f2bf(c1.x); afrag[5] = f2bf(c1.y);
        afrag[6] = f2bf(c1.z); afrag[7] = f2bf(c1.w);

        #pragma unroll
        for (int ct = 0; ct < 4; ++ct)
            acc[ct] = __builtin_amdgcn_mfma_f32_16x16x32_bf16(afrag, bfrag[ct], acc[ct], 0, 0, 0);
    }

    #pragma unroll
    for (int ct = 0; ct < 4; ++ct) {
        #pragma unroll
        for (int reg = 0; reg < 4; ++reg) {
            const int row = r0 + lk * 4 + reg;
            if (row < n) h1b[(size_t)row * HD1 + ct * 16 + lr] = (unsigned short)f2bf(acc[ct][reg]);
        }
    }

    float asv[4], adv[4];
    #pragma unroll
    for (int ct = 0; ct < 4; ++ct) { asv[ct] = a_src[ct * 16 + lr]; adv[ct] = a_dst[ct * 16 + lr]; }

    #pragma unroll
    for (int reg = 0; reg < 4; ++reg) {
        const int row = r0 + lk * 4 + reg;
        #pragma unroll
        for (int ct = 0; ct < 4; ++ct) {
            float s1 = acc[ct][reg] * asv[ct];
            float s2 = acc[ct][reg] * adv[ct];
            s1 += __shfl_xor(s1, 1); s1 += __shfl_xor(s1, 2);
            s1 += __shfl_xor(s1, 4); s1 += __shfl_xor(s1, 8);
            s2 += __shfl_xor(s2, 1); s2 += __shfl_xor(s2, 2);
            s2 += __shfl_xor(s2, 4); s2 += __shfl_xor(s2, 8);
            if (lr == 0 && row < n) {
                alsrc[row * HEADS + ct] = s1;
                aldst[row * HEADS + ct] = s2;
            }
        }
    }
}

// ---------------- Layer 1 aggregation: two-phase softmax, 8-wide batched bf16 gathers; hact in bf16 ----------------
__global__ __launch_bounds__(256) void k_aggr1(const unsigned short* __restrict__ h1b,
        const float* __restrict__ alsrc, const float* __restrict__ aldst, const float* __restrict__ b1,
        const int* __restrict__ rowstart, const int* __restrict__ counts, const int* __restrict__ ssrc,
        unsigned short* __restrict__ hactb, int n)
{
    const int wid  = (blockIdx.x * blockDim.x + threadIdx.x) >> 6;
    const int lane = threadIdx.x & 63;
    const int sub  = lane & 15;
    const int head = sub >> 2;

    int nid = wid * 4 + (lane >> 4);
    const bool valid = nid < n;
    if (!valid) nid = n - 1;

    const int rs  = rowstart[nid];
    const int cnt = valid ? counts[nid] : 0;

    int maxcnt = cnt;
    maxcnt = max(maxcnt, __shfl_xor(maxcnt, 16));
    maxcnt = max(maxcnt, __shfl_xor(maxcnt, 32));

    // Phase A: node-wide max over (edge, head) pairs.
    float m = -1e30f;
    {
        const float adA = aldst[nid * HEADS + (sub & 3)];
        const int npairs = cnt * 4, maxpairs = maxcnt * 4;
        for (int idx = sub; idx < maxpairs; idx += 16) {
            if (idx < npairs) {
                int s = ssrc[rs + (idx >> 2)];
                float l = alsrc[s * HEADS + (sub & 3)] + adA;
                l = l > 0.f ? l : NEG * l;
                m = fmaxf(m, l);
            }
        }
        #pragma unroll
        for (int off = 1; off < 16; off <<= 1) m = fmaxf(m, __shfl_xor(m, off));
    }

    // Phase B: 8-wide batched independent iterations (16 outstanding loads/lane).
    const float adB = aldst[nid * HEADS + head];
    float d = 0.f;
    float4 acc = make_float4(0.f, 0.f, 0.f, 0.f);
    for (int i0 = 0; i0 < maxcnt; i0 += 8) {
        int  sv[8]; bool on[8];
        #pragma unroll
        for (int u = 0; u < 8; ++u) {
            const int i = i0 + u;
            on[u] = i < cnt;
            sv[u] = on[u] ? ssrc[rs + i] : 0;
        }
        ushort4 hv[8]; float lv[8];
        #pragma unroll
        for (int u = 0; u < 8; ++u) {
            hv[u] = *(const ushort4*)(h1b + (size_t)sv[u] * HD1 + sub * 4);
            lv[u] = alsrc[sv[u] * HEADS + head];
        }
        #pragma unroll
        for (int u = 0; u < 8; ++u) {
            float l = lv[u] + adB;
            l = l > 0.f ? l : NEG * l;
            const float p = on[u] ? __expf(l - m) : 0.f;
            d += p;
            acc.x = fmaf(p, bf2f(hv[u].x), acc.x);
            acc.y = fmaf(p, bf2f(hv[u].y), acc.y);
            acc.z = fmaf(p, bf2f(hv[u].z), acc.z);
            acc.w = fmaf(p, bf2f(hv[u].w), acc.w);
        }
    }

    const float inv = 1.f / (d + 1e-16f);
    const float4 bv = *(const float4*)(b1 + sub * 4);
    float4 v;
    v.x = acc.x * inv + bv.x;  v.y = acc.y * inv + bv.y;
    v.z = acc.z * inv + bv.z;  v.w = acc.w * inv + bv.w;
    v.x = v.x > 0.f ? v.x : __expf(v.x) - 1.f;   // ELU
    v.y = v.y > 0.f ? v.y : __expf(v.y) - 1.f;
    v.z = v.z > 0.f ? v.z : __expf(v.z) - 1.f;
    v.w = v.w > 0.f ? v.w : __expf(v.w) - 1.f;
    if (valid) {
        ushort4 pk;
        pk.x = (unsigned short)f2bf(v.x);
        pk.y = (unsigned short)f2bf(v.y);
        pk.z = (unsigned short)f2bf(v.z);
        pk.w = (unsigned short)f2bf(v.w);
        *(ushort4*)(hactb + (size_t)nid * HD1 + sub * 4) = pk;
    }
}

// ---------------- Layer 2 transform: h2 = hact(bf16) @ W2 (64->40) + fused logits; h2 in bf16 ----------------
__global__ __launch_bounds__(64) void k_xform2(const unsigned short* __restrict__ hinb,
        const float* __restrict__ W2, const float* __restrict__ a_src, const float* __restrict__ a_dst,
        unsigned short* __restrict__ h2b, float* __restrict__ alsrc, float* __restrict__ aldst, int n)
{
    __shared__ float Ws[HD1 * OUT_CH];       // 10240 B
    const int t = threadIdx.x;
    #pragma unroll
    for (int i = 0; i < 10; ++i) ((float4*)Ws)[i * 64 + t] = ((const float4*)W2)[i * 64 + t];
    __syncthreads();

    const int r = blockIdx.x * 64 + t;
    if (r >= n) return;

    float acc[OUT_CH];
    #pragma unroll
    for (int j = 0; j < OUT_CH; ++j) acc[j] = 0.f;

    const ushort4* hr = (const ushort4*)(hinb + (size_t)r * HD1);
    for (int kq = 0; kq < 16; ++kq) {
        const ushort4 xb = hr[kq];
        const float xf[4] = { bf2f(xb.x), bf2f(xb.y), bf2f(xb.z), bf2f(xb.w) };
        #pragma unroll
        for (int kk = 0; kk < 4; ++kk) {
            const float xs = xf[kk];
            const float* wrow = Ws + (kq * 4 + kk) * OUT_CH;
            #pragma unroll
            for (int jq = 0; jq < 10; ++jq) {
                const float4 w = *(const float4*)(wrow + jq * 4);
                acc[jq * 4 + 0] = fmaf(xs, w.x, acc[jq * 4 + 0]);
                acc[jq * 4 + 1] = fmaf(xs, w.y, acc[jq * 4 + 1]);
                acc[jq * 4 + 2] = fmaf(xs, w.z, acc[jq * 4 + 2]);
                acc[jq * 4 + 3] = fmaf(xs, w.w, acc[jq * 4 + 3]);
            }
        }
    }

    float s1 = 0.f, s2 = 0.f;
    #pragma unroll
    for (int jq = 0; jq < 10; ++jq) {
        const float4 av = ((const float4*)a_src)[jq];
        const float4 dv = ((const float4*)a_dst)[jq];
        s1 += acc[jq*4+0] * av.x + acc[jq*4+1] * av.y + acc[jq*4+2] * av.z + acc[jq*4+3] * av.w;
        s2 += acc[jq*4+0] * dv.x + acc[jq*4+1] * dv.y + acc[jq*4+2] * dv.z + acc[jq*4+3] * dv.w;
        ushort4 pk;
        pk.x = (unsigned short)f2bf(acc[jq*4+0]);
        pk.y = (unsigned short)f2bf(acc[jq*4+1]);
        pk.z = (unsigned short)f2bf(acc[jq*4+2]);
        pk.w = (unsigned short)f2bf(acc[jq*4+3]);
        *(ushort4*)(h2b + (size_t)r * OUT_CH + jq * 4) = pk;
    }
    alsrc[r] = s1;
    aldst[r] = s2;
}

// ---------------- Layer 2 aggregation: two-phase, 8-wide batched + bias + log_softmax ----------------
__global__ __launch_bounds__(256) void k_aggr2(const unsigned short* __restrict__ h2b,
        const float* __restrict__ alsrc, const float* __restrict__ aldst, const float* __restrict__ b2,
        const int* __restrict__ rowstart, const int* __restrict__ counts, const int* __restrict__ ssrc,
        float* __restrict__ out, int n)
{
    const int wid  = (blockIdx.x * blockDim.x + threadIdx.x) >> 6;
    const int lane = threadIdx.x & 63;
    const int sub  = lane & 15;
    const bool act = sub < 10;
    const int subc = act ? sub : 0;

    int nid = wid * 4 + (lane >> 4);
    const bool valid = nid < n;
    if (!valid) nid = n - 1;

    const int rs  = rowstart[nid];
    const int cnt = valid ? counts[nid] : 0;

    int maxcnt = cnt;
    maxcnt = max(maxcnt, __shfl_xor(maxcnt, 16));
    maxcnt = max(maxcnt, __shfl_xor(maxcnt, 32));

    const float ad = aldst[nid];

    // Phase A: max over edges, lanes parallel (e = sub + 16k).
    float m = -1e30f;
    for (int e = sub; e < maxcnt; e += 16) {
        if (e < cnt) {
            int s = ssrc[rs + e];
            float l = alsrc[s] + ad;
            l = l > 0.f ? l : NEG * l;
            m = fmaxf(m, l);
        }
    }
    #pragma unroll
    for (int off = 1; off < 16; off <<= 1) m = fmaxf(m, __shfl_xor(m, off));

    // Phase B: 8-wide batched, bf16 ushort4 gathers.
    float d = 0.f;
    float4 acc = make_float4(0.f, 0.f, 0.f, 0.f);
    for (int i0 = 0; i0 < maxcnt; i0 += 8) {
        int  sv[8]; bool on[8];
        #pragma unroll
        for (int u = 0; u < 8; ++u) {
            const int i = i0 + u;
            on[u] = i < cnt;
            sv[u] = on[u] ? ssrc[rs + i] : 0;
        }
        ushort4 hv[8]; float lv[8];
        #pragma unroll
        for (int u = 0; u < 8; ++u) {
            hv[u] = *(const ushort4*)(h2b + (size_t)sv[u] * OUT_CH + subc * 4);
            lv[u] = alsrc[sv[u]];
        }
        #pragma unroll
        for (int u = 0; u < 8; ++u) {
            float l = lv[u] + ad;
            l = l > 0.f ? l : NEG * l;
            const float p = on[u] ? __expf(l - m) : 0.f;
            d += p;
            acc.x = fmaf(p, bf2f(hv[u].x), acc.x);
            acc.y = fmaf(p, bf2f(hv[u].y), acc.y);
            acc.z = fmaf(p, bf2f(hv[u].z), acc.z);
            acc.w = fmaf(p, bf2f(hv[u].w), acc.w);
        }
    }

    const float inv = 1.f / (d + 1e-16f);
    const float4 bv = *(const float4*)(b2 + subc * 4);
    float4 v;
    v.x = acc.x * inv + bv.x;  v.y = acc.y * inv + bv.y;
    v.z = acc.z * inv + bv.z;  v.w = acc.w * inv + bv.w;

    float mv = act ? fmaxf(fmaxf(v.x, v.y), fmaxf(v.z, v.w)) : -1e30f;
    #pragma unroll
    for (int off = 1; off < 16; off <<= 1) mv = fmaxf(mv, __shfl_xor(mv, off));
    float ex = act ? (__expf(v.x - mv) + __expf(v.y - mv) + __expf(v.z - mv) + __expf(v.w - mv)) : 0.f;
    #pragma unroll
    for (int off = 1; off < 16; off <<= 1) ex += __shfl_xor(ex, off);
    const float lse = mv + __logf(ex);

    if (valid && act) {
        *(float4*)(out + (size_t)nid * OUT_CH + sub * 4) =
            make_float4(v.x - lse, v.y - lse, v.z - lse, v.w - lse);
    }
}

extern "C" void kernel_launch(void* const* d_in, const int* in_sizes, int n_in,
                              void* d_out, int out_size, void* d_ws, size_t ws_size,
                              hipStream_t stream) {
    const float* x      = (const float*)d_in[0];
    const int*   ei     = (const int*)d_in[1];
    const float* W1     = (const float*)d_in[2];
    const float* a_src1 = (const float*)d_in[3];
    const float* a_dst1 = (const float*)d_in[4];
    const float* b1     = (const float*)d_in[5];
    const float* W2     = (const float*)d_in[6];
    const float* a_src2 = (const float*)d_in[7];
    const float* a_dst2 = (const float*)d_in[8];
    const float* b2     = (const float*)d_in[9];
    float* out = (float*)d_out;

    const int N = in_sizes[0] / IN_CH;
    const int E = in_sizes[1] / 2;
    const int B = (N + BRNG - 1) >> BSH;     // dst-buckets

    const int perBlk = 8192;
    const int nblkE  = (E + perBlk - 1) / perBlk;

    char* p = (char*)d_ws;
    auto alloc = [&](size_t bytes) -> void* {
        void* r = (void*)p;
        p += (bytes + 255) & ~(size_t)255;
        return r;
    };
    int*   counts   = (int*)alloc((size_t)N * 4);
    int*   rowstart = (int*)alloc((size_t)N * 4);
    int*   ssrc     = (int*)alloc((size_t)(E + N) * 4);
    int*   bcnt     = (int*)alloc((size_t)B * 4);
    int*   ebstart  = (int*)alloc((size_t)B * 4);
    int*   ebcur    = (int*)alloc((size_t)B * 4);
    int*   sstart   = (int*)alloc((size_t)B * 4);
    int*   partial  = (int*)alloc((size_t)B * nblkE * 4);   // transposed per-block histograms
    unsigned short* h1b   = (unsigned short*)alloc((size_t)N * HD1 * 2);    // bf16 messages L1
    unsigned short* h2b   = (unsigned short*)alloc((size_t)N * OUT_CH * 2); // bf16 messages L2
    unsigned short* hactb = (unsigned short*)alloc((size_t)N * HD1 * 2);    // bf16 hact
    float* alsrc1   = (float*)alloc((size_t)N * HEADS * 4);
    float* aldst1   = (float*)alloc((size_t)N * HEADS * 4);
    unsigned* epk   = (unsigned*)hactb;      // alias: epk dead before hactb is written (E*4 <= N*HD1*2)
    float* alsrc2 = alsrc1; float* aldst2 = aldst1;

    const int nblk64 = (N + 63) / 64;
    const int nblkAg = (N + 15) / 16;        // 4 nodes/wave, 4 waves/block

    k_bhist <<<nblkE, 256, 0, stream>>>(ei + E, partial, E, B, nblkE, perBlk);
    k_bscan <<<1, 512, 0, stream>>>(partial, nblkE, bcnt, ebstart, ebcur, sstart, B, N);
    k_bpart <<<nblkE, 256, 0, stream>>>(ei, ebcur, epk, E, B, perBlk);
    k_bcsr  <<<B, 256, 0, stream>>>(epk, ebstart, bcnt, sstart, rowstart, counts, ssrc, N);

    k_xform1 <<<nblk64, 256, 0, stream>>>(x, W1, a_src1, a_dst1, h1b, alsrc1, aldst1, N);
    k_aggr1  <<<nblkAg, 256, 0, stream>>>(h1b, alsrc1, aldst1, b1, rowstart, counts, ssrc, hactb, N);
    k_xform2 <<<nblk64, 64, 0, stream>>>(hactb, W2, a_src2, a_dst2, h2b, alsrc2, aldst2, N);
    k_aggr2  <<<nblkAg, 256, 0, stream>>>(h2b, alsrc2, aldst2, b2, rowstart, counts, ssrc, out, N);
}

// Round 17
// 142.833 us; speedup vs baseline: 1.1241x; 1.0007x over previous
//
#include <hip/hip_runtime.h>
#include <math.h>

static constexpr int IN_CH  = 256;
static constexpr int HD1    = 64;   // HEADS*HID
static constexpr int HEADS  = 4;
static constexpr int OUT_CH = 40;
static constexpr float NEG  = 0.2f;
static constexpr int BSH    = 7;    // 128 nodes per dst-bucket
static constexpr int BRNG   = 128;

typedef __attribute__((ext_vector_type(8))) short bf16x8;
typedef __attribute__((ext_vector_type(4))) short s16x4;
typedef __attribute__((ext_vector_type(4))) float f32x4;

static __device__ __forceinline__ short f2bf(float f) {
    union { float f; unsigned u; } v; v.f = f;
    unsigned r = v.u + 0x7FFFu + ((v.u >> 16) & 1u);
    return (short)(r >> 16);
}
static __device__ __forceinline__ float bf2f(unsigned short u) {
    union { unsigned u; float f; } v; v.u = ((unsigned)u) << 16;
    return v.f;
}

// ---------------- CSR build: no pre-zeroed memory anywhere ----------------
__global__ __launch_bounds__(256) void k_bhist(const int* __restrict__ dst, int* __restrict__ partial,
                                               int E, int B, int nb, int perBlk) {
    __shared__ int lcnt[4096];
    for (int i = threadIdx.x; i < B; i += 256) lcnt[i] = 0;
    __syncthreads();
    const int s0 = blockIdx.x * perBlk;
    const int s1 = min(s0 + perBlk, E);
    for (int i = s0 + threadIdx.x; i < s1; i += 256)
        atomicAdd(&lcnt[dst[i] >> BSH], 1);
    __syncthreads();
    for (int i = threadIdx.x; i < B; i += 256)
        partial[i * nb + blockIdx.x] = lcnt[i];   // transposed: bscan reads contiguously
}

__global__ __launch_bounds__(512) void k_bscan(const int* __restrict__ partial, int nb,
        int* __restrict__ bcnt, int* __restrict__ ebstart, int* __restrict__ ebcur,
        int* __restrict__ sstart, int B, int n) {
    __shared__ int es[512], ss[512];
    const int t = threadIdx.x;
    int ec = 0;
    if (t < B) {
        const int* pr = partial + (size_t)t * nb;
        #pragma unroll 4
        for (int b = 0; b < nb; ++b) ec += pr[b];    // contiguous, independent loads
    }
    int nodes = (t < B) ? min(n - (t << BSH), BRNG) : 0;
    es[t] = ec; ss[t] = ec + nodes;
    __syncthreads();
    #pragma unroll
    for (int off = 1; off < 512; off <<= 1) {        // Hillis-Steele inclusive scan
        int eu = 0, su = 0;
        if (t >= off) { eu = es[t - off]; su = ss[t - off]; }
        __syncthreads();
        if (t >= off) { es[t] += eu; ss[t] += su; }
        __syncthreads();
    }
    if (t < B) {
        const int e0 = es[t] - ec;                   // exclusive
        bcnt[t]    = ec;
        ebstart[t] = e0;
        ebcur[t]   = e0;
        sstart[t]  = ss[t] - (ec + nodes);
    }
}

// Edge record packed to 24 bits: src (17b) << 7 | (dst & 127).
__global__ __launch_bounds__(256) void k_bpart(const int* __restrict__ ei, int* __restrict__ ebcur,
        unsigned* __restrict__ epk, int E, int B, int perBlk) {
    __shared__ int lcnt[4096];
    __shared__ int lofs[4096];
    for (int i = threadIdx.x; i < B; i += 256) lcnt[i] = 0;
    __syncthreads();
    const int s0 = blockIdx.x * perBlk;
    const int s1 = min(s0 + perBlk, E);
    for (int i = s0 + threadIdx.x; i < s1; i += 256)
        atomicAdd(&lcnt[ei[E + i] >> BSH], 1);
    __syncthreads();
    for (int i = threadIdx.x; i < B; i += 256) {
        const int c = lcnt[i];
        lofs[i] = c ? atomicAdd(&ebcur[i], c) : 0;
        lcnt[i] = 0;
    }
    __syncthreads();
    for (int i = s0 + threadIdx.x; i < s1; i += 256) {
        const int d = ei[E + i], s = ei[i];
        const int b = d >> BSH;
        const int r = atomicAdd(&lcnt[b], 1);
        epk[lofs[b] + r] = ((unsigned)s << 7) | (unsigned)(d & (BRNG - 1));
    }
}

__global__ __launch_bounds__(256) void k_bcsr(const unsigned* __restrict__ epk,
        const int* __restrict__ ebstart, const int* __restrict__ bcnt, const int* __restrict__ sstart,
        int* __restrict__ rowstart, int* __restrict__ counts, int* __restrict__ ssrc, int n) {
    __shared__ int ncnt[BRNG], rloc[BRNG], cur[BRNG];
    const int b = blockIdx.x;
    const int t = threadIdx.x;
    const int n0 = b << BSH;
    const int nodes = min(n - n0, BRNG);
    const int ec = bcnt[b];
    const int e0 = ebstart[b];
    const int s0 = sstart[b];

    if (t < BRNG) ncnt[t] = (t < nodes) ? 1 : 0;   // self-loop seed
    __syncthreads();
    for (int i = t; i < ec; i += 256)
        atomicAdd(&ncnt[epk[e0 + i] & (BRNG - 1)], 1);
    __syncthreads();

    if (t < BRNG) rloc[t] = ncnt[t];
    __syncthreads();
    #pragma unroll
    for (int off = 1; off < BRNG; off <<= 1) {      // Hillis-Steele inclusive scan
        int u = 0;
        if (t < BRNG && t >= off) u = rloc[t - off];
        __syncthreads();
        if (t < BRNG) rloc[t] += u;
        __syncthreads();
    }

    if (t < nodes) {
        const int ex = rloc[t] - ncnt[t];
        rowstart[n0 + t] = s0 + ex;
        counts[n0 + t]   = ncnt[t];
        ssrc[s0 + ex]    = n0 + t;
        cur[t] = ex + 1;
    }
    __syncthreads();
    for (int i = t; i < ec; i += 256) {
        const unsigned e = epk[e0 + i];
        const int lo = (int)(e & (BRNG - 1));
        const int p = atomicAdd(&cur[lo], 1);
        ssrc[s0 + p] = (int)(e >> 7);
    }
}

// ---------------- Layer 1 transform: h1 = x @ W1 via bf16 MFMA + fused logits ----------------
// 2-slab-deep x prefetch: 4 outstanding 16B loads/lane (vs 2) to cover HBM latency.
__global__ __launch_bounds__(256) void k_xform1(const float* __restrict__ x,
        const float* __restrict__ W1, const float* __restrict__ a_src, const float* __restrict__ a_dst,
        unsigned short* __restrict__ h1b, float* __restrict__ alsrc, float* __restrict__ aldst, int n)
{
    __shared__ short W1T[64][264];          // 33792 B
    const int t = threadIdx.x;
    const int l = t & 63;
    const int w = t >> 6;

    {
        const int c = l;
        #pragma unroll
        for (int i = 0; i < 16; ++i) {
            const int kb = i * 16 + w * 4;
            s16x4 pk;
            pk[0] = f2bf(W1[(kb + 0) * 64 + c]);
            pk[1] = f2bf(W1[(kb + 1) * 64 + c]);
            pk[2] = f2bf(W1[(kb + 2) * 64 + c]);
            pk[3] = f2bf(W1[(kb + 3) * 64 + c]);
            *(s16x4*)&W1T[c][kb] = pk;
        }
    }
    __syncthreads();

    const int r0 = blockIdx.x * 64 + w * 16;
    const int lr = l & 15;
    const int lk = l >> 4;

    f32x4 acc[4];
    #pragma unroll
    for (int ct = 0; ct < 4; ++ct) acc[ct] = (f32x4){0.f, 0.f, 0.f, 0.f};

    int rowA = r0 + lr; if (rowA > n - 1) rowA = n - 1;
    const float* xrow = x + (size_t)rowA * IN_CH + lk * 8;

    // pipeline: 2 k-slabs in flight (4 x 16B loads outstanding per lane)
    float4 p0a = *(const float4*)(xrow);
    float4 p0b = *(const float4*)(xrow + 4);
    float4 p1a = *(const float4*)(xrow + 32);
    float4 p1b = *(const float4*)(xrow + 36);

    for (int ks = 0; ks < 8; ++ks) {
        bf16x8 bfrag[4];
        #pragma unroll
        for (int ct = 0; ct < 4; ++ct)
            bfrag[ct] = *(const bf16x8*)&W1T[ct * 16 + lr][ks * 32 + lk * 8];

        const float4 c0 = p0a, c1 = p0b;
        p0a = p1a; p0b = p1b;
        if (ks < 6) {                        // fetch slab ks+2
            p1a = *(const float4*)(xrow + (ks + 2) * 32);
            p1b = *(const float4*)(xrow + (ks + 2) * 32 + 4);
        }

        bf16x8 afrag;
        afrag[0] = f2bf(c0.x); afrag[1] = f2bf(c0.y);
        afrag[2] = f2bf(c0.z); afrag[3] = f2bf(c0.w);
        afrag[4] = f2bf(c1.x); afrag[5] = f2bf(c1.y);
        afrag[6] = f2bf(c1.z); afrag[7] = f2bf(c1.w);

        #pragma unroll
        for (int ct = 0; ct < 4; ++ct)
            acc[ct] = __builtin_amdgcn_mfma_f32_16x16x32_bf16(afrag, bfrag[ct], acc[ct], 0, 0, 0);
    }

    #pragma unroll
    for (int ct = 0; ct < 4; ++ct) {
        #pragma unroll
        for (int reg = 0; reg < 4; ++reg) {
            const int row = r0 + lk * 4 + reg;
            if (row < n) h1b[(size_t)row * HD1 + ct * 16 + lr] = (unsigned short)f2bf(acc[ct][reg]);
        }
    }

    float asv[4], adv[4];
    #pragma unroll
    for (int ct = 0; ct < 4; ++ct) { asv[ct] = a_src[ct * 16 + lr]; adv[ct] = a_dst[ct * 16 + lr]; }

    #pragma unroll
    for (int reg = 0; reg < 4; ++reg) {
        const int row = r0 + lk * 4 + reg;
        #pragma unroll
        for (int ct = 0; ct < 4; ++ct) {
            float s1 = acc[ct][reg] * asv[ct];
            float s2 = acc[ct][reg] * adv[ct];
            s1 += __shfl_xor(s1, 1); s1 += __shfl_xor(s1, 2);
            s1 += __shfl_xor(s1, 4); s1 += __shfl_xor(s1, 8);
            s2 += __shfl_xor(s2, 1); s2 += __shfl_xor(s2, 2);
            s2 += __shfl_xor(s2, 4); s2 += __shfl_xor(s2, 8);
            if (lr == 0 && row < n) {
                alsrc[row * HEADS + ct] = s1;
                aldst[row * HEADS + ct] = s2;
            }
        }
    }
}

// ---------------- Layer 1 aggregation: two-phase softmax, 8-wide batched bf16 gathers; hact in bf16 ----------------
__global__ __launch_bounds__(256) void k_aggr1(const unsigned short* __restrict__ h1b,
        const float* __restrict__ alsrc, const float* __restrict__ aldst, const float* __restrict__ b1,
        const int* __restrict__ rowstart, const int* __restrict__ counts, const int* __restrict__ ssrc,
        unsigned short* __restrict__ hactb, int n)
{
    const int wid  = (blockIdx.x * blockDim.x + threadIdx.x) >> 6;
    const int lane = threadIdx.x & 63;
    const int sub  = lane & 15;
    const int head = sub >> 2;

    int nid = wid * 4 + (lane >> 4);
    const bool valid = nid < n;
    if (!valid) nid = n - 1;

    const int rs  = rowstart[nid];
    const int cnt = valid ? counts[nid] : 0;

    int maxcnt = cnt;
    maxcnt = max(maxcnt, __shfl_xor(maxcnt, 16));
    maxcnt = max(maxcnt, __shfl_xor(maxcnt, 32));

    // Phase A: node-wide max over (edge, head) pairs.
    float m = -1e30f;
    {
        const float adA = aldst[nid * HEADS + (sub & 3)];
        const int npairs = cnt * 4, maxpairs = maxcnt * 4;
        for (int idx = sub; idx < maxpairs; idx += 16) {
            if (idx < npairs) {
                int s = ssrc[rs + (idx >> 2)];
                float l = alsrc[s * HEADS + (sub & 3)] + adA;
                l = l > 0.f ? l : NEG * l;
                m = fmaxf(m, l);
            }
        }
        #pragma unroll
        for (int off = 1; off < 16; off <<= 1) m = fmaxf(m, __shfl_xor(m, off));
    }

    // Phase B: 8-wide batched independent iterations (16 outstanding loads/lane).
    const float adB = aldst[nid * HEADS + head];
    float d = 0.f;
    float4 acc = make_float4(0.f, 0.f, 0.f, 0.f);
    for (int i0 = 0; i0 < maxcnt; i0 += 8) {
        int  sv[8]; bool on[8];
        #pragma unroll
        for (int u = 0; u < 8; ++u) {
            const int i = i0 + u;
            on[u] = i < cnt;
            sv[u] = on[u] ? ssrc[rs + i] : 0;
        }
        ushort4 hv[8]; float lv[8];
        #pragma unroll
        for (int u = 0; u < 8; ++u) {
            hv[u] = *(const ushort4*)(h1b + (size_t)sv[u] * HD1 + sub * 4);
            lv[u] = alsrc[sv[u] * HEADS + head];
        }
        #pragma unroll
        for (int u = 0; u < 8; ++u) {
            float l = lv[u] + adB;
            l = l > 0.f ? l : NEG * l;
            const float p = on[u] ? __expf(l - m) : 0.f;
            d += p;
            acc.x = fmaf(p, bf2f(hv[u].x), acc.x);
            acc.y = fmaf(p, bf2f(hv[u].y), acc.y);
            acc.z = fmaf(p, bf2f(hv[u].z), acc.z);
            acc.w = fmaf(p, bf2f(hv[u].w), acc.w);
        }
    }

    const float inv = 1.f / (d + 1e-16f);
    const float4 bv = *(const float4*)(b1 + sub * 4);
    float4 v;
    v.x = acc.x * inv + bv.x;  v.y = acc.y * inv + bv.y;
    v.z = acc.z * inv + bv.z;  v.w = acc.w * inv + bv.w;
    v.x = v.x > 0.f ? v.x : __expf(v.x) - 1.f;   // ELU
    v.y = v.y > 0.f ? v.y : __expf(v.y) - 1.f;
    v.z = v.z > 0.f ? v.z : __expf(v.z) - 1.f;
    v.w = v.w > 0.f ? v.w : __expf(v.w) - 1.f;
    if (valid) {
        ushort4 pk;
        pk.x = (unsigned short)f2bf(v.x);
        pk.y = (unsigned short)f2bf(v.y);
        pk.z = (unsigned short)f2bf(v.z);
        pk.w = (unsigned short)f2bf(v.w);
        *(ushort4*)(hactb + (size_t)nid * HD1 + sub * 4) = pk;
    }
}

// ---------------- Layer 2 transform: h2 = hact(bf16) @ W2 (64->40) + fused logits; h2 in bf16 ----------------
__global__ __launch_bounds__(64) void k_xform2(const unsigned short* __restrict__ hinb,
        const float* __restrict__ W2, const float* __restrict__ a_src, const float* __restrict__ a_dst,
        unsigned short* __restrict__ h2b, float* __restrict__ alsrc, float* __restrict__ aldst, int n)
{
    __shared__ float Ws[HD1 * OUT_CH];       // 10240 B
    const int t = threadIdx.x;
    #pragma unroll
    for (int i = 0; i < 10; ++i) ((float4*)Ws)[i * 64 + t] = ((const float4*)W2)[i * 64 + t];
    __syncthreads();

    const int r = blockIdx.x * 64 + t;
    if (r >= n) return;

    float acc[OUT_CH];
    #pragma unroll
    for (int j = 0; j < OUT_CH; ++j) acc[j] = 0.f;

    const ushort4* hr = (const ushort4*)(hinb + (size_t)r * HD1);
    for (int kq = 0; kq < 16; ++kq) {
        const ushort4 xb = hr[kq];
        const float xf[4] = { bf2f(xb.x), bf2f(xb.y), bf2f(xb.z), bf2f(xb.w) };
        #pragma unroll
        for (int kk = 0; kk < 4; ++kk) {
            const float xs = xf[kk];
            const float* wrow = Ws + (kq * 4 + kk) * OUT_CH;
            #pragma unroll
            for (int jq = 0; jq < 10; ++jq) {
                const float4 w = *(const float4*)(wrow + jq * 4);
                acc[jq * 4 + 0] = fmaf(xs, w.x, acc[jq * 4 + 0]);
                acc[jq * 4 + 1] = fmaf(xs, w.y, acc[jq * 4 + 1]);
                acc[jq * 4 + 2] = fmaf(xs, w.z, acc[jq * 4 + 2]);
                acc[jq * 4 + 3] = fmaf(xs, w.w, acc[jq * 4 + 3]);
            }
        }
    }

    float s1 = 0.f, s2 = 0.f;
    #pragma unroll
    for (int jq = 0; jq < 10; ++jq) {
        const float4 av = ((const float4*)a_src)[jq];
        const float4 dv = ((const float4*)a_dst)[jq];
        s1 += acc[jq*4+0] * av.x + acc[jq*4+1] * av.y + acc[jq*4+2] * av.z + acc[jq*4+3] * av.w;
        s2 += acc[jq*4+0] * dv.x + acc[jq*4+1] * dv.y + acc[jq*4+2] * dv.z + acc[jq*4+3] * dv.w;
        ushort4 pk;
        pk.x = (unsigned short)f2bf(acc[jq*4+0]);
        pk.y = (unsigned short)f2bf(acc[jq*4+1]);
        pk.z = (unsigned short)f2bf(acc[jq*4+2]);
        pk.w = (unsigned short)f2bf(acc[jq*4+3]);
        *(ushort4*)(h2b + (size_t)r * OUT_CH + jq * 4) = pk;
    }
    alsrc[r] = s1;
    aldst[r] = s2;
}

// ---------------- Layer 2 aggregation: two-phase, 8-wide batched + bias + log_softmax ----------------
__global__ __launch_bounds__(256) void k_aggr2(const unsigned short* __restrict__ h2b,
        const float* __restrict__ alsrc, const float* __restrict__ aldst, const float* __restrict__ b2,
        const int* __restrict__ rowstart, const int* __restrict__ counts, const int* __restrict__ ssrc,
        float* __restrict__ out, int n)
{
    const int wid  = (blockIdx.x * blockDim.x + threadIdx.x) >> 6;
    const int lane = threadIdx.x & 63;
    const int sub  = lane & 15;
    const bool act = sub < 10;
    const int subc = act ? sub : 0;

    int nid = wid * 4 + (lane >> 4);
    const bool valid = nid < n;
    if (!valid) nid = n - 1;

    const int rs  = rowstart[nid];
    const int cnt = valid ? counts[nid] : 0;

    int maxcnt = cnt;
    maxcnt = max(maxcnt, __shfl_xor(maxcnt, 16));
    maxcnt = max(maxcnt, __shfl_xor(maxcnt, 32));

    const float ad = aldst[nid];

    // Phase A: max over edges, lanes parallel (e = sub + 16k).
    float m = -1e30f;
    for (int e = sub; e < maxcnt; e += 16) {
        if (e < cnt) {
            int s = ssrc[rs + e];
            float l = alsrc[s] + ad;
            l = l > 0.f ? l : NEG * l;
            m = fmaxf(m, l);
        }
    }
    #pragma unroll
    for (int off = 1; off < 16; off <<= 1) m = fmaxf(m, __shfl_xor(m, off));

    // Phase B: 8-wide batched, bf16 ushort4 gathers.
    float d = 0.f;
    float4 acc = make_float4(0.f, 0.f, 0.f, 0.f);
    for (int i0 = 0; i0 < maxcnt; i0 += 8) {
        int  sv[8]; bool on[8];
        #pragma unroll
        for (int u = 0; u < 8; ++u) {
            const int i = i0 + u;
            on[u] = i < cnt;
            sv[u] = on[u] ? ssrc[rs + i] : 0;
        }
        ushort4 hv[8]; float lv[8];
        #pragma unroll
        for (int u = 0; u < 8; ++u) {
            hv[u] = *(const ushort4*)(h2b + (size_t)sv[u] * OUT_CH + subc * 4);
            lv[u] = alsrc[sv[u]];
        }
        #pragma unroll
        for (int u = 0; u < 8; ++u) {
            float l = lv[u] + ad;
            l = l > 0.f ? l : NEG * l;
            const float p = on[u] ? __expf(l - m) : 0.f;
            d += p;
            acc.x = fmaf(p, bf2f(hv[u].x), acc.x);
            acc.y = fmaf(p, bf2f(hv[u].y), acc.y);
            acc.z = fmaf(p, bf2f(hv[u].z), acc.z);
            acc.w = fmaf(p, bf2f(hv[u].w), acc.w);
        }
    }

    const float inv = 1.f / (d + 1e-16f);
    const float4 bv = *(const float4*)(b2 + subc * 4);
    float4 v;
    v.x = acc.x * inv + bv.x;  v.y = acc.y * inv + bv.y;
    v.z = acc.z * inv + bv.z;  v.w = acc.w * inv + bv.w;

    float mv = act ? fmaxf(fmaxf(v.x, v.y), fmaxf(v.z, v.w)) : -1e30f;
    #pragma unroll
    for (int off = 1; off < 16; off <<= 1) mv = fmaxf(mv, __shfl_xor(mv, off));
    float ex = act ? (__expf(v.x - mv) + __expf(v.y - mv) + __expf(v.z - mv) + __expf(v.w - mv)) : 0.f;
    #pragma unroll
    for (int off = 1; off < 16; off <<= 1) ex += __shfl_xor(ex, off);
    const float lse = mv + __logf(ex);

    if (valid && act) {
        *(float4*)(out + (size_t)nid * OUT_CH + sub * 4) =
            make_float4(v.x - lse, v.y - lse, v.z - lse, v.w - lse);
    }
}

extern "C" void kernel_launch(void* const* d_in, const int* in_sizes, int n_in,
                              void* d_out, int out_size, void* d_ws, size_t ws_size,
                              hipStream_t stream) {
    const float* x      = (const float*)d_in[0];
    const int*   ei     = (const int*)d_in[1];
    const float* W1     = (const float*)d_in[2];
    const float* a_src1 = (const float*)d_in[3];
    const float* a_dst1 = (const float*)d_in[4];
    const float* b1     = (const float*)d_in[5];
    const float* W2     = (const float*)d_in[6];
    const float* a_src2 = (const float*)d_in[7];
    const float* a_dst2 = (const float*)d_in[8];
    const float* b2     = (const float*)d_in[9];
    float* out = (float*)d_out;

    const int N = in_sizes[0] / IN_CH;
    const int E = in_sizes[1] / 2;
    const int B = (N + BRNG - 1) >> BSH;     // dst-buckets

    const int perBlk = 8192;
    const int nblkE  = (E + perBlk - 1) / perBlk;

    char* p = (char*)d_ws;
    auto alloc = [&](size_t bytes) -> void* {
        void* r = (void*)p;
        p += (bytes + 255) & ~(size_t)255;
        return r;
    };
    int*   counts   = (int*)alloc((size_t)N * 4);
    int*   rowstart = (int*)alloc((size_t)N * 4);
    int*   ssrc     = (int*)alloc((size_t)(E + N) * 4);
    int*   bcnt     = (int*)alloc((size_t)B * 4);
    int*   ebstart  = (int*)alloc((size_t)B * 4);
    int*   ebcur    = (int*)alloc((size_t)B * 4);
    int*   sstart   = (int*)alloc((size_t)B * 4);
    int*   partial  = (int*)alloc((size_t)B * nblkE * 4);   // transposed per-block histograms
    unsigned short* h1b   = (unsigned short*)alloc((size_t)N * HD1 * 2);    // bf16 messages L1
    unsigned short* h2b   = (unsigned short*)alloc((size_t)N * OUT_CH * 2); // bf16 messages L2
    unsigned short* hactb = (unsigned short*)alloc((size_t)N * HD1 * 2);    // bf16 hact
    float* alsrc1   = (float*)alloc((size_t)N * HEADS * 4);
    float* aldst1   = (float*)alloc((size_t)N * HEADS * 4);
    unsigned* epk   = (unsigned*)hactb;      // alias: epk dead before hactb is written (E*4 <= N*HD1*2)
    float* alsrc2 = alsrc1; float* aldst2 = aldst1;

    const int nblk64 = (N + 63) / 64;
    const int nblkAg = (N + 15) / 16;        // 4 nodes/wave, 4 waves/block

    k_bhist <<<nblkE, 256, 0, stream>>>(ei + E, partial, E, B, nblkE, perBlk);
    k_bscan <<<1, 512, 0, stream>>>(partial, nblkE, bcnt, ebstart, ebcur, sstart, B, N);
    k_bpart <<<nblkE, 256, 0, stream>>>(ei, ebcur, epk, E, B, perBlk);
    k_bcsr  <<<B, 256, 0, stream>>>(epk, ebstart, bcnt, sstart, rowstart, counts, ssrc, N);

    k_xform1 <<<nblk64, 256, 0, stream>>>(x, W1, a_src1, a_dst1, h1b, alsrc1, aldst1, N);
    k_aggr1  <<<nblkAg, 256, 0, stream>>>(h1b, alsrc1, aldst1, b1, rowstart, counts, ssrc, hactb, N);
    k_xform2 <<<nblk64, 64, 0, stream>>>(hactb, W2, a_src2, a_dst2, h2b, alsrc2, aldst2, N);
    k_aggr2  <<<nblkAg, 256, 0, stream>>>(h2b, alsrc2, aldst2, b2, rowstart, counts, ssrc, out, N);
}